// Round 7
// baseline (6686.613 us; speedup 1.0000x reference)
//
#include <hip/hip_runtime.h>
#include <hip/hip_bf16.h>
#include <stdint.h>
#include <math.h>

#define NROWS 4096
#define DIM   256
#define NHEAD 4
#define HDK   64
#define LNEPS 1e-6f
#define FLT_TINY 1.17549435e-38f

// ---------------- block reductions (256 threads) ----------------
__device__ __forceinline__ float blockReduceSum(float v, float* red) {
  int t = threadIdx.x;
  red[t] = v; __syncthreads();
  for (int s = 128; s > 0; s >>= 1) {
    if (t < s) red[t] += red[t + s];
    __syncthreads();
  }
  float r = red[0]; __syncthreads();
  return r;
}

__device__ __forceinline__ double blockReduceSumD(double v, double* red) {
  int t = threadIdx.x;
  red[t] = v; __syncthreads();
  for (int s = 128; s > 0; s >>= 1) {
    if (t < s) red[t] += red[t + s];
    __syncthreads();
  }
  double r = red[0]; __syncthreads();
  return r;
}

__device__ __forceinline__ float blockReduceMax(float v, float* red) {
  int t = threadIdx.x;
  red[t] = v; __syncthreads();
  for (int s = 128; s > 0; s >>= 1) {
    if (t < s) red[t] = fmaxf(red[t], red[t + s]);
    __syncthreads();
  }
  float r = red[0]; __syncthreads();
  return r;
}

// ------- JAX threefry2x32 (20 rounds) — hand-verified vs KAT 0x6b200159,0x99ba4efe -------
__device__ __forceinline__ uint32_t rotl32(uint32_t v, int d) {
  return (v << d) | (v >> (32 - d));
}

__device__ __forceinline__ void threefry2x32(uint32_t k0, uint32_t k1,
                                             uint32_t x0, uint32_t x1,
                                             uint32_t& o0, uint32_t& o1) {
  uint32_t ks0 = k0, ks1 = k1, ks2 = k0 ^ k1 ^ 0x1BD11BDAu;
  x0 += ks0; x1 += ks1;
#define TF_R(r) { x0 += x1; x1 = rotl32(x1, r); x1 ^= x0; }
  TF_R(13) TF_R(15) TF_R(26) TF_R(6)
  x0 += ks1; x1 += ks2 + 1u;
  TF_R(17) TF_R(29) TF_R(16) TF_R(24)
  x0 += ks2; x1 += ks0 + 2u;
  TF_R(13) TF_R(15) TF_R(26) TF_R(6)
  x0 += ks0; x1 += ks1 + 3u;
  TF_R(17) TF_R(29) TF_R(16) TF_R(24)
  x0 += ks1; x1 += ks2 + 4u;
  TF_R(13) TF_R(15) TF_R(26) TF_R(6)
  x0 += ks2; x1 += ks0 + 5u;
#undef TF_R
  o0 = x0; o1 = x1;
}

__device__ __forceinline__ float jax_uniform_from_bits(uint32_t bits) {
  uint32_t fb = (bits >> 9) | 0x3f800000u;
  float f = __uint_as_float(fb) - 1.0f;      // [0, 1)
  return fmaxf(FLT_TINY, f);
}

// ---------------- K0: detect mask dtype ----------------
// flag: 0=i32, 1=u8/bool, 2=f32, 3=bf16, 4=i64, 5=f64
__global__ void k_detect_mask(const uint32_t* __restrict__ m, int* __restrict__ flag) {
  __shared__ int s_u8, s_bf16, s_f32one, s_f64hi, s_ones, s_oddnz, s_other;
  int t = threadIdx.x;
  if (t == 0) { s_u8 = 0; s_bf16 = 0; s_f32one = 0; s_f64hi = 0; s_ones = 0; s_oddnz = 0; s_other = 0; }
  __syncthreads();
  int u8v = 0, bf16v = 0, f32v = 0, f64v = 0, onesv = 0, oddv = 0, otherv = 0;
  for (int i = t; i < 262144; i += 256) {   // scan first 1 MB
    uint32_t w = m[i];
    if (w == 0u) continue;
    if (i & 1) oddv = 1;
    if (w == 1u) { onesv = 1; continue; }
    uint32_t b0 = w & 0xFFu, b1 = (w >> 8) & 0xFFu;
    uint32_t b2 = (w >> 16) & 0xFFu, b3 = w >> 24;
    if (b0 <= 1u && b1 <= 1u && b2 <= 1u && b3 <= 1u) { u8v = 1; continue; }
    if (w == 0x3F800000u) { f32v = 1; continue; }
    if (w == 0x00003F80u || w == 0x3F803F80u) { bf16v = 1; continue; }
    if (w == 0x3FF00000u && (i & 1)) { f64v = 1; continue; }
    otherv = 1;
  }
  if (u8v) s_u8 = 1;
  if (bf16v) s_bf16 = 1;
  if (f32v) s_f32one = 1;
  if (f64v) s_f64hi = 1;
  if (onesv) s_ones = 1;
  if (oddv) s_oddnz = 1;
  if (otherv) s_other = 1;
  __syncthreads();
  if (t == 0) {
    int f;
    if (s_u8) f = 1;
    else if (s_bf16) f = 3;
    else if (s_f32one) f = 2;
    else if (s_f64hi && !s_ones) f = 5;
    else if (s_ones && !s_oddnz) f = 4;
    else f = 0;
    *flag = f;
  }
}

__device__ __forceinline__ bool mask_at(const void* mask, int mtype, size_t idx) {
  switch (mtype) {
    case 1:  return ((const uint8_t*)mask)[idx] != 0;
    case 0:  return ((const int*)mask)[idx] != 0;
    case 2:  return ((const float*)mask)[idx] != 0.0f;
    case 3:  return ((const uint16_t*)mask)[idx] != 0;
    case 4:  return ((const unsigned long long*)mask)[idx] != 0ull;
    default: return ((const unsigned long long*)mask)[idx] != 0ull;
  }
}

// ---------------- K1: x0 = LN(x_input) ----------------
__global__ void k_ln0(const float* __restrict__ x, const float* __restrict__ alpha,
                      const float* __restrict__ bias, float* __restrict__ out) {
  __shared__ float red[256];
  int row = blockIdx.x, t = threadIdx.x;
  float v = x[row * DIM + t];
  float mu = blockReduceSum(v, red) * (1.0f / DIM);
  float d = v - mu;
  float var = blockReduceSum(d * d, red) * (1.0f / (DIM - 1));
  float denom = sqrtf(var) + LNEPS;
  out[row * DIM + t] = alpha[t] * d / denom + bias[t];
}

// ------- K2: x1 = LN(elu(x0 @ W1^T + b1)) -------
__global__ void k_fc_elu_ln(const float* __restrict__ xin, const float* __restrict__ W,
                            const float* __restrict__ b, const float* __restrict__ alpha,
                            const float* __restrict__ bias, float* __restrict__ out) {
  __shared__ float xr[256];
  __shared__ float red[256];
  int row = blockIdx.x, t = threadIdx.x;
  xr[t] = xin[row * DIM + t];
  __syncthreads();
  const float4* w4 = (const float4*)(W + t * DIM);
  const float4* x4 = (const float4*)xr;
  float acc = b[t];
#pragma unroll 8
  for (int u = 0; u < DIM / 4; ++u) {
    float4 a = x4[u], w = w4[u];
    acc = fmaf(a.x, w.x, acc); acc = fmaf(a.y, w.y, acc);
    acc = fmaf(a.z, w.z, acc); acc = fmaf(a.w, w.w, acc);
  }
  float e = acc > 0.0f ? acc : expm1f(acc);
  float mu = blockReduceSum(e, red) * (1.0f / DIM);
  float d = e - mu;
  float var = blockReduceSum(d * d, red) * (1.0f / (DIM - 1));
  float denom = sqrtf(var) + LNEPS;
  out[row * DIM + t] = alpha[t] * d / denom + bias[t];
}

// ------- K3: q/k/v projections -------
__global__ void k_qkv(const float* __restrict__ xin,
                      const float* __restrict__ Wq, const float* __restrict__ bq,
                      const float* __restrict__ Wk, const float* __restrict__ bk,
                      const float* __restrict__ Wv, const float* __restrict__ bv,
                      float* __restrict__ q, float* __restrict__ k, float* __restrict__ v) {
  __shared__ float xr[256];
  int row = blockIdx.x, t = threadIdx.x;
  const float* W; const float* b; float* o;
  if (blockIdx.y == 0)      { W = Wq; b = bq; o = q; }
  else if (blockIdx.y == 1) { W = Wk; b = bk; o = k; }
  else                      { W = Wv; b = bv; o = v; }
  xr[t] = xin[row * DIM + t];
  __syncthreads();
  const float4* w4 = (const float4*)(W + t * DIM);
  const float4* x4 = (const float4*)xr;
  float acc = b[t];
#pragma unroll 8
  for (int u = 0; u < DIM / 4; ++u) {
    float4 a = x4[u], w = w4[u];
    acc = fmaf(a.x, w.x, acc); acc = fmaf(a.y, w.y, acc);
    acc = fmaf(a.z, w.z, acc); acc = fmaf(a.w, w.w, acc);
  }
  o[row * DIM + t] = acc;
}

// ------- K4: attention per (row, head) -------
__global__ void k_attn(const float* __restrict__ q, const float* __restrict__ k,
                       const float* __restrict__ v, const void* __restrict__ mask,
                       const int* __restrict__ mflag, float* __restrict__ out) {
  __shared__ float sc[4096];
  __shared__ float qr[64];
  __shared__ float red[256];
  int row = blockIdx.x, h = blockIdx.y, t = threadIdx.x;
  int mtype = *mflag;
  if (t < 64) qr[t] = q[row * DIM + h * HDK + t];
  __syncthreads();
  float lmax = -3.402823466e38f;
  const float4* q4 = (const float4*)qr;
  size_t mbase = (size_t)row * NROWS;
  for (int m = t; m < NROWS; m += 256) {
    float s;
    if (mask_at(mask, mtype, mbase + m)) {
      s = -1e9f;
    } else {
      const float4* k4 = (const float4*)(k + m * DIM + h * HDK);
      float acc = 0.0f;
#pragma unroll
      for (int u = 0; u < HDK / 4; ++u) {
        float4 a = q4[u], w = k4[u];
        acc = fmaf(a.x, w.x, acc); acc = fmaf(a.y, w.y, acc);
        acc = fmaf(a.z, w.z, acc); acc = fmaf(a.w, w.w, acc);
      }
      s = acc * 0.125f;
    }
    sc[m] = s;
    lmax = fmaxf(lmax, s);
  }
  float M = blockReduceMax(lmax, red);
  float lsum = 0.0f;
  for (int m = t; m < NROWS; m += 256) {
    float p = expf(sc[m] - M);
    sc[m] = p;
    lsum += p;
  }
  float S = blockReduceSum(lsum, red);
  int d = t & 63, g = t >> 6;
  float acc = 0.0f;
  int m0 = g * 1024, m1 = m0 + 1024;
  for (int m = m0; m < m1; ++m) acc = fmaf(sc[m], v[m * DIM + h * HDK + d], acc);
  red[t] = acc;
  __syncthreads();
  if (g == 0) {
    float o = (red[d] + red[64 + d] + red[128 + d] + red[192 + d]) / S;
    out[row * DIM + h * HDK + d] = o;
  }
}

// ------- K5: x3 = LN(elu(att @ Wo^T + bo + x1)) -------
__global__ void k_out_ln(const float* __restrict__ att, const float* __restrict__ Wo,
                         const float* __restrict__ bo, const float* __restrict__ x1,
                         const float* __restrict__ alpha, const float* __restrict__ bias,
                         float* __restrict__ out) {
  __shared__ float xr[256];
  __shared__ float red[256];
  int row = blockIdx.x, t = threadIdx.x;
  xr[t] = att[row * DIM + t];
  __syncthreads();
  const float4* w4 = (const float4*)(Wo + t * DIM);
  const float4* x4 = (const float4*)xr;
  float acc = bo[t];
#pragma unroll 8
  for (int u = 0; u < DIM / 4; ++u) {
    float4 a = x4[u], w = w4[u];
    acc = fmaf(a.x, w.x, acc); acc = fmaf(a.y, w.y, acc);
    acc = fmaf(a.z, w.z, acc); acc = fmaf(a.w, w.w, acc);
  }
  float x2 = acc + x1[row * DIM + t];
  float e = x2 > 0.0f ? x2 : expm1f(x2);
  float mu = blockReduceSum(e, red) * (1.0f / DIM);
  float d = e - mu;
  float var = blockReduceSum(d * d, red) * (1.0f / (DIM - 1));
  float denom = sqrtf(var) + LNEPS;
  out[row * DIM + t] = alpha[t] * d / denom + bias[t];
}

// ------- K6: logits -> rowsum-scale -> softmax -> gumbel argmax (partitionable stream) -------
__global__ void k_final(const float* __restrict__ x3, const int* __restrict__ qidx,
                        const int* __restrict__ kidx, float* __restrict__ outp) {
  __shared__ float  sc[4096];
  __shared__ float  qe[256];
  __shared__ double redd[256];
  __shared__ float  red[256];
  __shared__ int    redi[256];
  __shared__ float  redp[256];
  int row = blockIdx.x, t = threadIdx.x;
  int qi = qidx[row];
  qe[t] = x3[qi * DIM + t];
  __syncthreads();
  const float4* q4 = (const float4*)qe;
  for (int c = t; c < NROWS; c += 256) {
    int kj = kidx[c];
    const float4* k4 = (const float4*)(x3 + kj * DIM);
    float acc = 0.0f;
#pragma unroll 8
    for (int u = 0; u < DIM / 4; ++u) {
      float4 a = q4[u], w = k4[u];
      acc = fmaf(a.x, w.x, acc); acc = fmaf(a.y, w.y, acc);
      acc = fmaf(a.z, w.z, acc); acc = fmaf(a.w, w.w, acc);
    }
    sc[c] = acc;
  }
  __syncthreads();
  double part = 0.0;
  for (int c = t; c < NROWS; c += 256) part += (double)sc[c];
  double S = blockReduceSumD(part, redd);
  double inv = 1.0 / S;
  float lmax = -3.402823466e38f;
  for (int c = t; c < NROWS; c += 256) {
    float z = (float)((double)sc[c] * inv);
    sc[c] = z;
    lmax = fmaxf(lmax, z);
  }
  float M = blockReduceMax(lmax, red);
  double esum = 0.0;
  for (int c = t; c < NROWS; c += 256) {
    float p = expf(sc[c] - M);
    sc[c] = p;
    esum += (double)p;
  }
  float E = (float)blockReduceSumD(esum, redd);
  // gumbel + argmax — JAX >=0.4.36 partitionable threefry:
  // bits[i] = o0 ^ o1 of threefry2x32(key, (hi32(i)=0, lo32(i)=i))
  uint32_t rbase = (uint32_t)row * (uint32_t)NROWS;
  float best = -3.402823466e38f; int bidx = 0x7fffffff; float bp = 0.0f;
  for (int c = t; c < NROWS; c += 256) {
    uint32_t o0, o1;
    threefry2x32(0u, 42u, 0u, rbase + (uint32_t)c, o0, o1);
    uint32_t bits = o0 ^ o1;
    float u = jax_uniform_from_bits(bits);
    float g = -logf(-logf(u));
    float p = sc[c] / E;
    float val = p + g;
    if (val > best) { best = val; bidx = c; bp = p; }
  }
  red[t] = best; redi[t] = bidx; redp[t] = bp;
  __syncthreads();
  for (int s = 128; s > 0; s >>= 1) {
    if (t < s) {
      float vb = red[t + s];
      if (vb > red[t] || (vb == red[t] && redi[t + s] < redi[t])) {
        red[t] = vb; redi[t] = redi[t + s]; redp[t] = redp[t + s];
      }
    }
    __syncthreads();
  }
  if (t == 0) {
    outp[row]         = (float)redi[0];   // sel
    outp[NROWS + row] = redp[0];          // ll
  }
}

extern "C" void kernel_launch(void* const* d_in, const int* in_sizes, int n_in,
                              void* d_out, int out_size, void* d_ws, size_t ws_size,
                              hipStream_t stream) {
  const float* x_input = (const float*)d_in[0];
  const void*  mask    = (const void*)d_in[1];
  const int*   qidx    = (const int*)d_in[2];
  const int*   kidx    = (const int*)d_in[3];
  const float* alpha0  = (const float*)d_in[4];
  const float* bias0   = (const float*)d_in[5];
  const float* W1      = (const float*)d_in[6];
  const float* b1      = (const float*)d_in[7];
  const float* alpha1  = (const float*)d_in[8];
  const float* bias1   = (const float*)d_in[9];
  const float* alpha2  = (const float*)d_in[10];
  const float* bias2   = (const float*)d_in[11];
  const float* Wq = (const float*)d_in[12]; const float* bq = (const float*)d_in[13];
  const float* Wk = (const float*)d_in[14]; const float* bk = (const float*)d_in[15];
  const float* Wv = (const float*)d_in[16]; const float* bv = (const float*)d_in[17];
  const float* Wo = (const float*)d_in[18]; const float* bo = (const float*)d_in[19];

  float* ws = (float*)d_ws;
  const size_t MAT = (size_t)NROWS * DIM;  // 1M elements = 4MB
  float* x0  = ws + 0 * MAT;
  float* x1  = ws + 1 * MAT;
  float* q   = ws + 2 * MAT;
  float* k   = ws + 3 * MAT;
  float* v   = ws + 4 * MAT;
  float* att = ws + 5 * MAT;
  float* x3  = ws + 6 * MAT;
  int*   mflag = (int*)(ws + 7 * MAT);
  float* out = (float*)d_out;

  k_detect_mask<<<1, 256, 0, stream>>>((const uint32_t*)mask, mflag);
  k_ln0<<<NROWS, 256, 0, stream>>>(x_input, alpha0, bias0, x0);
  k_fc_elu_ln<<<NROWS, 256, 0, stream>>>(x0, W1, b1, alpha1, bias1, x1);
  k_qkv<<<dim3(NROWS, 3), 256, 0, stream>>>(x1, Wq, bq, Wk, bk, Wv, bv, q, k, v);
  k_attn<<<dim3(NROWS, NHEAD), 256, 0, stream>>>(q, k, v, mask, mflag, att);
  k_out_ln<<<NROWS, 256, 0, stream>>>(att, Wo, bo, x1, alpha2, bias2, x3);
  k_final<<<NROWS, 256, 0, stream>>>(x3, qidx, kidx, out);
}

// Round 8
// 5518.493 us; speedup vs baseline: 1.2117x; 1.2117x over previous
//
#include <hip/hip_runtime.h>
#include <hip/hip_bf16.h>
#include <stdint.h>
#include <math.h>

#define NROWS 4096
#define DIM   256
#define NHEAD 4
#define HDK   64
#define LNEPS 1e-6f
#define FLT_TINY 1.17549435e-38f

// ---------------- block reductions (256 threads) ----------------
__device__ __forceinline__ float blockReduceSum(float v, float* red) {
  int t = threadIdx.x;
  red[t] = v; __syncthreads();
  for (int s = 128; s > 0; s >>= 1) {
    if (t < s) red[t] += red[t + s];
    __syncthreads();
  }
  float r = red[0]; __syncthreads();
  return r;
}

__device__ __forceinline__ double blockReduceSumD(double v, double* red) {
  int t = threadIdx.x;
  red[t] = v; __syncthreads();
  for (int s = 128; s > 0; s >>= 1) {
    if (t < s) red[t] += red[t + s];
    __syncthreads();
  }
  double r = red[0]; __syncthreads();
  return r;
}

__device__ __forceinline__ float blockReduceMax(float v, float* red) {
  int t = threadIdx.x;
  red[t] = v; __syncthreads();
  for (int s = 128; s > 0; s >>= 1) {
    if (t < s) red[t] = fmaxf(red[t], red[t + s]);
    __syncthreads();
  }
  float r = red[0]; __syncthreads();
  return r;
}

// ------- JAX threefry2x32 (20 rounds) — KAT-verified -------
__device__ __forceinline__ uint32_t rotl32(uint32_t v, int d) {
  return (v << d) | (v >> (32 - d));
}

__device__ __forceinline__ void threefry2x32(uint32_t k0, uint32_t k1,
                                             uint32_t x0, uint32_t x1,
                                             uint32_t& o0, uint32_t& o1) {
  uint32_t ks0 = k0, ks1 = k1, ks2 = k0 ^ k1 ^ 0x1BD11BDAu;
  x0 += ks0; x1 += ks1;
#define TF_R(r) { x0 += x1; x1 = rotl32(x1, r); x1 ^= x0; }
  TF_R(13) TF_R(15) TF_R(26) TF_R(6)
  x0 += ks1; x1 += ks2 + 1u;
  TF_R(17) TF_R(29) TF_R(16) TF_R(24)
  x0 += ks2; x1 += ks0 + 2u;
  TF_R(13) TF_R(15) TF_R(26) TF_R(6)
  x0 += ks0; x1 += ks1 + 3u;
  TF_R(17) TF_R(29) TF_R(16) TF_R(24)
  x0 += ks1; x1 += ks2 + 4u;
  TF_R(13) TF_R(15) TF_R(26) TF_R(6)
  x0 += ks2; x1 += ks0 + 5u;
#undef TF_R
  o0 = x0; o1 = x1;
}

__device__ __forceinline__ float jax_uniform_from_bits(uint32_t bits) {
  uint32_t fb = (bits >> 9) | 0x3f800000u;
  float f = __uint_as_float(fb) - 1.0f;      // [0, 1)
  return fmaxf(FLT_TINY, f);
}

// ---------------- K0: detect mask dtype ----------------
// flag: 0=i32, 1=u8/bool, 2=f32, 3=bf16, 4=i64, 5=f64
__global__ void k_detect_mask(const uint32_t* __restrict__ m, int* __restrict__ flag) {
  __shared__ int s_u8, s_bf16, s_f32one, s_f64hi, s_ones, s_oddnz, s_other;
  int t = threadIdx.x;
  if (t == 0) { s_u8 = 0; s_bf16 = 0; s_f32one = 0; s_f64hi = 0; s_ones = 0; s_oddnz = 0; s_other = 0; }
  __syncthreads();
  int u8v = 0, bf16v = 0, f32v = 0, f64v = 0, onesv = 0, oddv = 0, otherv = 0;
  for (int i = t; i < 262144; i += 256) {
    uint32_t w = m[i];
    if (w == 0u) continue;
    if (i & 1) oddv = 1;
    if (w == 1u) { onesv = 1; continue; }
    uint32_t b0 = w & 0xFFu, b1 = (w >> 8) & 0xFFu;
    uint32_t b2 = (w >> 16) & 0xFFu, b3 = w >> 24;
    if (b0 <= 1u && b1 <= 1u && b2 <= 1u && b3 <= 1u) { u8v = 1; continue; }
    if (w == 0x3F800000u) { f32v = 1; continue; }
    if (w == 0x00003F80u || w == 0x3F803F80u) { bf16v = 1; continue; }
    if (w == 0x3FF00000u && (i & 1)) { f64v = 1; continue; }
    otherv = 1;
  }
  if (u8v) s_u8 = 1;
  if (bf16v) s_bf16 = 1;
  if (f32v) s_f32one = 1;
  if (f64v) s_f64hi = 1;
  if (onesv) s_ones = 1;
  if (oddv) s_oddnz = 1;
  if (otherv) s_other = 1;
  __syncthreads();
  if (t == 0) {
    int f;
    if (s_u8) f = 1;
    else if (s_bf16) f = 3;
    else if (s_f32one) f = 2;
    else if (s_f64hi && !s_ones) f = 5;
    else if (s_ones && !s_oddnz) f = 4;
    else f = 0;
    *flag = f;
  }
}

__device__ __forceinline__ bool mask_at(const void* mask, int mtype, size_t idx) {
  switch (mtype) {
    case 1:  return ((const uint8_t*)mask)[idx] != 0;
    case 0:  return ((const int*)mask)[idx] != 0;
    case 2:  return ((const float*)mask)[idx] != 0.0f;
    case 3:  return ((const uint16_t*)mask)[idx] != 0;
    case 4:  return ((const unsigned long long*)mask)[idx] != 0ull;
    default: return ((const unsigned long long*)mask)[idx] != 0ull;
  }
}

// ---------------- K1: x0 = LN(x_input) ----------------
__global__ void k_ln0(const float* __restrict__ x, const float* __restrict__ alpha,
                      const float* __restrict__ bias, float* __restrict__ out) {
  __shared__ float red[256];
  int row = blockIdx.x, t = threadIdx.x;
  float v = x[row * DIM + t];
  float mu = blockReduceSum(v, red) * (1.0f / DIM);
  float d = v - mu;
  float var = blockReduceSum(d * d, red) * (1.0f / (DIM - 1));
  float denom = sqrtf(var) + LNEPS;
  out[row * DIM + t] = alpha[t] * d / denom + bias[t];
}

// ------- K2: x1 = LN(elu(x0 @ W1^T + b1)) -------
__global__ void k_fc_elu_ln(const float* __restrict__ xin, const float* __restrict__ W,
                            const float* __restrict__ b, const float* __restrict__ alpha,
                            const float* __restrict__ bias, float* __restrict__ out) {
  __shared__ float xr[256];
  __shared__ float red[256];
  int row = blockIdx.x, t = threadIdx.x;
  xr[t] = xin[row * DIM + t];
  __syncthreads();
  const float4* w4 = (const float4*)(W + t * DIM);
  const float4* x4 = (const float4*)xr;
  float acc = b[t];
#pragma unroll 8
  for (int u = 0; u < DIM / 4; ++u) {
    float4 a = x4[u], w = w4[u];
    acc = fmaf(a.x, w.x, acc); acc = fmaf(a.y, w.y, acc);
    acc = fmaf(a.z, w.z, acc); acc = fmaf(a.w, w.w, acc);
  }
  float e = acc > 0.0f ? acc : expm1f(acc);
  float mu = blockReduceSum(e, red) * (1.0f / DIM);
  float d = e - mu;
  float var = blockReduceSum(d * d, red) * (1.0f / (DIM - 1));
  float denom = sqrtf(var) + LNEPS;
  out[row * DIM + t] = alpha[t] * d / denom + bias[t];
}

// ------- K3: q/k/v projections -------
__global__ void k_qkv(const float* __restrict__ xin,
                      const float* __restrict__ Wq, const float* __restrict__ bq,
                      const float* __restrict__ Wk, const float* __restrict__ bk,
                      const float* __restrict__ Wv, const float* __restrict__ bv,
                      float* __restrict__ q, float* __restrict__ k, float* __restrict__ v) {
  __shared__ float xr[256];
  int row = blockIdx.x, t = threadIdx.x;
  const float* W; const float* b; float* o;
  if (blockIdx.y == 0)      { W = Wq; b = bq; o = q; }
  else if (blockIdx.y == 1) { W = Wk; b = bk; o = k; }
  else                      { W = Wv; b = bv; o = v; }
  xr[t] = xin[row * DIM + t];
  __syncthreads();
  const float4* w4 = (const float4*)(W + t * DIM);
  const float4* x4 = (const float4*)xr;
  float acc = b[t];
#pragma unroll 8
  for (int u = 0; u < DIM / 4; ++u) {
    float4 a = x4[u], w = w4[u];
    acc = fmaf(a.x, w.x, acc); acc = fmaf(a.y, w.y, acc);
    acc = fmaf(a.z, w.z, acc); acc = fmaf(a.w, w.w, acc);
  }
  o[row * DIM + t] = acc;
}

// ------- K4: flash-style attention, 32-row strip per (strip, head) block -------
// 256 threads = 4 waves; wave w owns rows w*8 .. w*8+7 of the strip.
__global__ __launch_bounds__(256) void k_attn2(
    const float* __restrict__ q, const float* __restrict__ k,
    const float* __restrict__ v, const void* __restrict__ mask,
    const int* __restrict__ mflag, float* __restrict__ out) {
  __shared__ float kT[64 * 65];        // [d][m] padded: 16.6 KB
  __shared__ float v_l[64 * 64];       // [m][d]: 16 KB
  __shared__ float p_l[32 * 64];       // [r][m]: 8 KB
  __shared__ float q_l[32 * 64];       // [r][d]: 8 KB
  const float4* q_l4 = (const float4*)q_l;
  const float4* p_l4 = (const float4*)p_l;
  float4* v_l4 = (float4*)v_l;

  int h = blockIdx.y;
  int r0 = blockIdx.x * 32;
  int t = threadIdx.x;
  int wid = t >> 6, lane = t & 63;
  int mtype = *mflag;

  // load q strip (32 x 64)
  for (int i = t; i < 2048; i += 256) {
    int r = i >> 6, d = i & 63;
    q_l[r * 64 + d] = q[(size_t)(r0 + r) * DIM + h * HDK + d];
  }

  float o_acc[8], mreg[8], lreg[8], alph[8];
#pragma unroll
  for (int j = 0; j < 8; ++j) { o_acc[j] = 0.0f; mreg[j] = -3.0e38f; lreg[j] = 0.0f; }

  for (int mt = 0; mt < 64; ++mt) {
    int m0 = mt * 64;
    __syncthreads();   // previous tile fully consumed
    // stage K (transposed, padded) and V tiles
    for (int i = t; i < 1024; i += 256) {
      int r = i >> 4, d4 = i & 15;
      float4 kv = *(const float4*)(k + (size_t)(m0 + r) * DIM + h * HDK + d4 * 4);
      kT[(d4 * 4 + 0) * 65 + r] = kv.x;
      kT[(d4 * 4 + 1) * 65 + r] = kv.y;
      kT[(d4 * 4 + 2) * 65 + r] = kv.z;
      kT[(d4 * 4 + 3) * 65 + r] = kv.w;
      v_l4[r * 16 + d4] = *(const float4*)(v + (size_t)(m0 + r) * DIM + h * HDK + d4 * 4);
    }
    __syncthreads();   // tiles ready

    // S = q . k^T for own 8 rows; lane = column (m within tile)
    float accS[8];
#pragma unroll
    for (int j = 0; j < 8; ++j) accS[j] = 0.0f;
    for (int d4 = 0; d4 < 16; ++d4) {
      float k0 = kT[(d4 * 4 + 0) * 65 + lane];
      float k1 = kT[(d4 * 4 + 1) * 65 + lane];
      float k2 = kT[(d4 * 4 + 2) * 65 + lane];
      float k3 = kT[(d4 * 4 + 3) * 65 + lane];
#pragma unroll
      for (int j = 0; j < 8; ++j) {
        float4 q4 = q_l4[(wid * 8 + j) * 16 + d4];
        accS[j] = fmaf(q4.x, k0, fmaf(q4.y, k1, fmaf(q4.z, k2, fmaf(q4.w, k3, accS[j]))));
      }
    }
    // online softmax update per row (wave-local)
#pragma unroll
    for (int j = 0; j < 8; ++j) {
      int r = wid * 8 + j;
      bool masked = mask_at(mask, mtype, (size_t)(r0 + r) * NROWS + m0 + lane);
      float s = masked ? -1e9f : accS[j] * 0.125f;
      float tm = s;
      tm = fmaxf(tm, __shfl_xor(tm, 32));
      tm = fmaxf(tm, __shfl_xor(tm, 16));
      tm = fmaxf(tm, __shfl_xor(tm, 8));
      tm = fmaxf(tm, __shfl_xor(tm, 4));
      tm = fmaxf(tm, __shfl_xor(tm, 2));
      tm = fmaxf(tm, __shfl_xor(tm, 1));
      float m_new = fmaxf(mreg[j], tm);
      float p = expf(s - m_new);
      float ps = p;
      ps += __shfl_xor(ps, 32);
      ps += __shfl_xor(ps, 16);
      ps += __shfl_xor(ps, 8);
      ps += __shfl_xor(ps, 4);
      ps += __shfl_xor(ps, 2);
      ps += __shfl_xor(ps, 1);
      float a = expf(mreg[j] - m_new);
      lreg[j] = lreg[j] * a + ps;
      mreg[j] = m_new;
      alph[j] = a;
      p_l[r * 64 + lane] = p;
    }
    // PV accumulate (lane = d); same wave wrote p for these rows — no barrier needed
#pragma unroll
    for (int j = 0; j < 8; ++j) o_acc[j] *= alph[j];
    for (int c4 = 0; c4 < 16; ++c4) {
      float v0 = v_l[(c4 * 4 + 0) * 64 + lane];
      float v1 = v_l[(c4 * 4 + 1) * 64 + lane];
      float v2 = v_l[(c4 * 4 + 2) * 64 + lane];
      float v3 = v_l[(c4 * 4 + 3) * 64 + lane];
#pragma unroll
      for (int j = 0; j < 8; ++j) {
        float4 p4 = p_l4[(wid * 8 + j) * 16 + c4];
        o_acc[j] = fmaf(p4.x, v0, fmaf(p4.y, v1, fmaf(p4.z, v2, fmaf(p4.w, v3, o_acc[j]))));
      }
    }
  }
#pragma unroll
  for (int j = 0; j < 8; ++j) {
    int r = wid * 8 + j;
    out[(size_t)(r0 + r) * DIM + h * HDK + lane] = o_acc[j] / lreg[j];
  }
}

// ------- K5: x3 = LN(elu(att @ Wo^T + bo + x1)) -------
__global__ void k_out_ln(const float* __restrict__ att, const float* __restrict__ Wo,
                         const float* __restrict__ bo, const float* __restrict__ x1,
                         const float* __restrict__ alpha, const float* __restrict__ bias,
                         float* __restrict__ out) {
  __shared__ float xr[256];
  __shared__ float red[256];
  int row = blockIdx.x, t = threadIdx.x;
  xr[t] = att[row * DIM + t];
  __syncthreads();
  const float4* w4 = (const float4*)(Wo + t * DIM);
  const float4* x4 = (const float4*)xr;
  float acc = bo[t];
#pragma unroll 8
  for (int u = 0; u < DIM / 4; ++u) {
    float4 a = x4[u], w = w4[u];
    acc = fmaf(a.x, w.x, acc); acc = fmaf(a.y, w.y, acc);
    acc = fmaf(a.z, w.z, acc); acc = fmaf(a.w, w.w, acc);
  }
  float x2 = acc + x1[row * DIM + t];
  float e = x2 > 0.0f ? x2 : expm1f(x2);
  float mu = blockReduceSum(e, red) * (1.0f / DIM);
  float d = e - mu;
  float var = blockReduceSum(d * d, red) * (1.0f / (DIM - 1));
  float denom = sqrtf(var) + LNEPS;
  out[row * DIM + t] = alpha[t] * d / denom + bias[t];
}

// ------- K6a: build keT2[d2][c] = (x3[kidx[c]][2*d2], x3[kidx[c]][2*d2+1]) -------
__global__ void k_transpose_ke(const float* __restrict__ x3, const int* __restrict__ kidx,
                               float2* __restrict__ keT2) {
  __shared__ float tile[64 * 65];
  int cb = blockIdx.x, db = blockIdx.y;   // 64 x 4
  int t = threadIdx.x;
  for (int i = t; i < 4096; i += 256) {
    int ci = i >> 6, di = i & 63;
    int kj = kidx[cb * 64 + ci];
    tile[ci * 65 + di] = x3[(size_t)kj * DIM + db * 64 + di];
  }
  __syncthreads();
  for (int i = t; i < 2048; i += 256) {
    int di2 = i >> 6, ci = i & 63;   // di2 in 0..31
    keT2[(size_t)(db * 32 + di2) * NROWS + cb * 64 + ci] =
        make_float2(tile[ci * 65 + di2 * 2], tile[ci * 65 + di2 * 2 + 1]);
  }
}

// ------- K6b: 3-row strips: logits GEMM (LDS) -> rowsum -> softmax -> gumbel argmax -------
#define FR 3
__global__ __launch_bounds__(256) void k_final2(
    const float* __restrict__ x3, const float2* __restrict__ keT2,
    const int* __restrict__ qidx, float* __restrict__ outp) {
  __shared__ float  slog[FR * 4096];   // 48 KB
  __shared__ float2 sqe[FR * 128];     // 3 KB
  __shared__ double redd[256];
  __shared__ float  red[256];
  __shared__ int    redi[256];
  __shared__ float  redp[256];
  int r0 = blockIdx.x * FR;
  int nr = NROWS - r0; if (nr > FR) nr = FR;
  int t = threadIdx.x;
  // gather qe rows (zero pad unused)
  for (int i = t; i < FR * 128; i += 256) {
    int j = i >> 7, d2 = i & 127;
    if (r0 + j < NROWS) {
      int qi = qidx[r0 + j];
      sqe[j * 128 + d2] = ((const float2*)(x3 + (size_t)qi * DIM))[d2];
    } else {
      sqe[j * 128 + d2] = make_float2(0.0f, 0.0f);
    }
  }
  __syncthreads();
  // logits GEMM: each thread handles 16 columns
  for (int c = t; c < NROWS; c += 256) {
    float a0 = 0.0f, a1 = 0.0f, a2 = 0.0f;
#pragma unroll 8
    for (int d2 = 0; d2 < 128; ++d2) {
      float2 kv = keT2[(size_t)d2 * NROWS + c];
      float2 q0 = sqe[0 * 128 + d2];
      float2 q1 = sqe[1 * 128 + d2];
      float2 q2 = sqe[2 * 128 + d2];
      a0 = fmaf(q0.x, kv.x, fmaf(q0.y, kv.y, a0));
      a1 = fmaf(q1.x, kv.x, fmaf(q1.y, kv.y, a1));
      a2 = fmaf(q2.x, kv.x, fmaf(q2.y, kv.y, a2));
    }
    slog[0 * 4096 + c] = a0;
    slog[1 * 4096 + c] = a1;
    slog[2 * 4096 + c] = a2;
  }
  __syncthreads();
  // per-row finalize (identical numerics to the passing per-row kernel)
  for (int j = 0; j < nr; ++j) {
    int row = r0 + j;
    float* sc = &slog[j * 4096];
    double part = 0.0;
    for (int c = t; c < NROWS; c += 256) part += (double)sc[c];
    double S = blockReduceSumD(part, redd);
    double inv = 1.0 / S;
    float lmax = -3.402823466e38f;
    for (int c = t; c < NROWS; c += 256) {
      float z = (float)((double)sc[c] * inv);
      sc[c] = z;
      lmax = fmaxf(lmax, z);
    }
    float M = blockReduceMax(lmax, red);
    double esum = 0.0;
    for (int c = t; c < NROWS; c += 256) {
      float p = expf(sc[c] - M);
      sc[c] = p;
      esum += (double)p;
    }
    float E = (float)blockReduceSumD(esum, redd);
    uint32_t rbase = (uint32_t)row * (uint32_t)NROWS;
    float best = -3.402823466e38f; int bidx = 0x7fffffff; float bp = 0.0f;
    for (int c = t; c < NROWS; c += 256) {
      uint32_t o0, o1;
      threefry2x32(0u, 42u, 0u, rbase + (uint32_t)c, o0, o1);
      uint32_t bits = o0 ^ o1;
      float u = jax_uniform_from_bits(bits);
      float g = -logf(-logf(u));
      float p = sc[c] / E;
      float val = p + g;
      if (val > best) { best = val; bidx = c; bp = p; }
    }
    red[t] = best; redi[t] = bidx; redp[t] = bp;
    __syncthreads();
    for (int s = 128; s > 0; s >>= 1) {
      if (t < s) {
        float vb = red[t + s];
        if (vb > red[t] || (vb == red[t] && redi[t + s] < redi[t])) {
          red[t] = vb; redi[t] = redi[t + s]; redp[t] = redp[t + s];
        }
      }
      __syncthreads();
    }
    if (t == 0) {
      outp[row]         = (float)redi[0];
      outp[NROWS + row] = redp[0];
    }
    __syncthreads();
  }
}

extern "C" void kernel_launch(void* const* d_in, const int* in_sizes, int n_in,
                              void* d_out, int out_size, void* d_ws, size_t ws_size,
                              hipStream_t stream) {
  const float* x_input = (const float*)d_in[0];
  const void*  mask    = (const void*)d_in[1];
  const int*   qidx    = (const int*)d_in[2];
  const int*   kidx    = (const int*)d_in[3];
  const float* alpha0  = (const float*)d_in[4];
  const float* bias0   = (const float*)d_in[5];
  const float* W1      = (const float*)d_in[6];
  const float* b1      = (const float*)d_in[7];
  const float* alpha1  = (const float*)d_in[8];
  const float* bias1   = (const float*)d_in[9];
  const float* alpha2  = (const float*)d_in[10];
  const float* bias2   = (const float*)d_in[11];
  const float* Wq = (const float*)d_in[12]; const float* bq = (const float*)d_in[13];
  const float* Wk = (const float*)d_in[14]; const float* bk = (const float*)d_in[15];
  const float* Wv = (const float*)d_in[16]; const float* bv = (const float*)d_in[17];
  const float* Wo = (const float*)d_in[18]; const float* bo = (const float*)d_in[19];

  float* ws = (float*)d_ws;
  const size_t MAT = (size_t)NROWS * DIM;  // 1M elements = 4MB
  float*  x0   = ws + 0 * MAT;
  float*  x1   = ws + 1 * MAT;
  float*  q    = ws + 2 * MAT;
  float*  k    = ws + 3 * MAT;
  float*  v    = ws + 4 * MAT;
  float*  att  = ws + 5 * MAT;
  float*  x3   = ws + 6 * MAT;
  float2* keT2 = (float2*)(ws + 7 * MAT);          // 4 MB
  int*    mflag = (int*)(ws + 9 * MAT);
  float*  out = (float*)d_out;

  k_detect_mask<<<1, 256, 0, stream>>>((const uint32_t*)mask, mflag);
  k_ln0<<<NROWS, 256, 0, stream>>>(x_input, alpha0, bias0, x0);
  k_fc_elu_ln<<<NROWS, 256, 0, stream>>>(x0, W1, b1, alpha1, bias1, x1);
  k_qkv<<<dim3(NROWS, 3), 256, 0, stream>>>(x1, Wq, bq, Wk, bk, Wv, bv, q, k, v);
  k_attn2<<<dim3(NROWS / 32, NHEAD), 256, 0, stream>>>(q, k, v, mask, mflag, att);
  k_out_ln<<<NROWS, 256, 0, stream>>>(att, Wo, bo, x1, alpha2, bias2, x3);
  k_transpose_ke<<<dim3(64, 4), 256, 0, stream>>>(x3, kidx, keT2);
  k_final2<<<(NROWS + FR - 1) / FR, 256, 0, stream>>>(x3, keT2, qidx, out);
}

// Round 9
// 2165.908 us; speedup vs baseline: 3.0872x; 2.5479x over previous
//
#include <hip/hip_runtime.h>
#include <hip/hip_bf16.h>
#include <stdint.h>
#include <math.h>

#define NROWS 4096
#define DIM   256
#define NHEAD 4
#define HDK   64
#define LNEPS 1e-6f
#define FLT_TINY 1.17549435e-38f

// ---------------- block reductions (256 threads) ----------------
__device__ __forceinline__ float blockReduceSum(float v, float* red) {
  int t = threadIdx.x;
  red[t] = v; __syncthreads();
  for (int s = 128; s > 0; s >>= 1) {
    if (t < s) red[t] += red[t + s];
    __syncthreads();
  }
  float r = red[0]; __syncthreads();
  return r;
}

__device__ __forceinline__ double blockReduceSumD(double v, double* red) {
  int t = threadIdx.x;
  red[t] = v; __syncthreads();
  for (int s = 128; s > 0; s >>= 1) {
    if (t < s) red[t] += red[t + s];
    __syncthreads();
  }
  double r = red[0]; __syncthreads();
  return r;
}

__device__ __forceinline__ float blockReduceMax(float v, float* red) {
  int t = threadIdx.x;
  red[t] = v; __syncthreads();
  for (int s = 128; s > 0; s >>= 1) {
    if (t < s) red[t] = fmaxf(red[t], red[t + s]);
    __syncthreads();
  }
  float r = red[0]; __syncthreads();
  return r;
}

// ------- JAX threefry2x32 (20 rounds) — KAT-verified -------
__device__ __forceinline__ uint32_t rotl32(uint32_t v, int d) {
  return (v << d) | (v >> (32 - d));
}

__device__ __forceinline__ void threefry2x32(uint32_t k0, uint32_t k1,
                                             uint32_t x0, uint32_t x1,
                                             uint32_t& o0, uint32_t& o1) {
  uint32_t ks0 = k0, ks1 = k1, ks2 = k0 ^ k1 ^ 0x1BD11BDAu;
  x0 += ks0; x1 += ks1;
#define TF_R(r) { x0 += x1; x1 = rotl32(x1, r); x1 ^= x0; }
  TF_R(13) TF_R(15) TF_R(26) TF_R(6)
  x0 += ks1; x1 += ks2 + 1u;
  TF_R(17) TF_R(29) TF_R(16) TF_R(24)
  x0 += ks2; x1 += ks0 + 2u;
  TF_R(13) TF_R(15) TF_R(26) TF_R(6)
  x0 += ks0; x1 += ks1 + 3u;
  TF_R(17) TF_R(29) TF_R(16) TF_R(24)
  x0 += ks1; x1 += ks2 + 4u;
  TF_R(13) TF_R(15) TF_R(26) TF_R(6)
  x0 += ks2; x1 += ks0 + 5u;
#undef TF_R
  o0 = x0; o1 = x1;
}

__device__ __forceinline__ float jax_uniform_from_bits(uint32_t bits) {
  uint32_t fb = (bits >> 9) | 0x3f800000u;
  float f = __uint_as_float(fb) - 1.0f;      // [0, 1)
  return fmaxf(FLT_TINY, f);
}

// ---------------- K0: detect mask dtype ----------------
// flag: 0=i32, 1=u8/bool, 2=f32, 3=bf16, 4=i64, 5=f64
__global__ void k_detect_mask(const uint32_t* __restrict__ m, int* __restrict__ flag) {
  __shared__ int s_u8, s_bf16, s_f32one, s_f64hi, s_ones, s_oddnz, s_other;
  int t = threadIdx.x;
  if (t == 0) { s_u8 = 0; s_bf16 = 0; s_f32one = 0; s_f64hi = 0; s_ones = 0; s_oddnz = 0; s_other = 0; }
  __syncthreads();
  int u8v = 0, bf16v = 0, f32v = 0, f64v = 0, onesv = 0, oddv = 0, otherv = 0;
  for (int i = t; i < 262144; i += 256) {
    uint32_t w = m[i];
    if (w == 0u) continue;
    if (i & 1) oddv = 1;
    if (w == 1u) { onesv = 1; continue; }
    uint32_t b0 = w & 0xFFu, b1 = (w >> 8) & 0xFFu;
    uint32_t b2 = (w >> 16) & 0xFFu, b3 = w >> 24;
    if (b0 <= 1u && b1 <= 1u && b2 <= 1u && b3 <= 1u) { u8v = 1; continue; }
    if (w == 0x3F800000u) { f32v = 1; continue; }
    if (w == 0x00003F80u || w == 0x3F803F80u) { bf16v = 1; continue; }
    if (w == 0x3FF00000u && (i & 1)) { f64v = 1; continue; }
    otherv = 1;
  }
  if (u8v) s_u8 = 1;
  if (bf16v) s_bf16 = 1;
  if (f32v) s_f32one = 1;
  if (f64v) s_f64hi = 1;
  if (onesv) s_ones = 1;
  if (oddv) s_oddnz = 1;
  if (otherv) s_other = 1;
  __syncthreads();
  if (t == 0) {
    int f;
    if (s_u8) f = 1;
    else if (s_bf16) f = 3;
    else if (s_f32one) f = 2;
    else if (s_f64hi && !s_ones) f = 5;
    else if (s_ones && !s_oddnz) f = 4;
    else f = 0;
    *flag = f;
  }
}

__device__ __forceinline__ bool mask_at(const void* mask, int mtype, size_t idx) {
  switch (mtype) {
    case 1:  return ((const uint8_t*)mask)[idx] != 0;
    case 0:  return ((const int*)mask)[idx] != 0;
    case 2:  return ((const float*)mask)[idx] != 0.0f;
    case 3:  return ((const uint16_t*)mask)[idx] != 0;
    case 4:  return ((const unsigned long long*)mask)[idx] != 0ull;
    default: return ((const unsigned long long*)mask)[idx] != 0ull;
  }
}

// ------- K0b: pack mask into bit matrix: word[row*64 + w] bit lane = mask[row][w*64+lane] -------
__global__ __launch_bounds__(256) void k_mask_pack(const void* __restrict__ mask,
                                                   const int* __restrict__ mflag,
                                                   unsigned long long* __restrict__ bits) {
  int row = blockIdx.x, t = threadIdx.x;
  int wid = t >> 6, lane = t & 63;
  int mtype = *mflag;
  for (int it = 0; it < 16; ++it) {
    int w = it * 4 + wid;                       // word 0..63
    size_t idx = (size_t)row * NROWS + (size_t)w * 64 + lane;
    bool m = mask_at(mask, mtype, idx);
    unsigned long long b = __ballot(m);
    if (lane == 0) bits[(size_t)row * 64 + w] = b;
  }
}

// ---------------- K1: x0 = LN(x_input) ----------------
__global__ void k_ln0(const float* __restrict__ x, const float* __restrict__ alpha,
                      const float* __restrict__ bias, float* __restrict__ out) {
  __shared__ float red[256];
  int row = blockIdx.x, t = threadIdx.x;
  float v = x[row * DIM + t];
  float mu = blockReduceSum(v, red) * (1.0f / DIM);
  float d = v - mu;
  float var = blockReduceSum(d * d, red) * (1.0f / (DIM - 1));
  float denom = sqrtf(var) + LNEPS;
  out[row * DIM + t] = alpha[t] * d / denom + bias[t];
}

// ------- K2: x1 = LN(elu(x0 @ W1^T + b1)) -------
__global__ void k_fc_elu_ln(const float* __restrict__ xin, const float* __restrict__ W,
                            const float* __restrict__ b, const float* __restrict__ alpha,
                            const float* __restrict__ bias, float* __restrict__ out) {
  __shared__ float xr[256];
  __shared__ float red[256];
  int row = blockIdx.x, t = threadIdx.x;
  xr[t] = xin[row * DIM + t];
  __syncthreads();
  const float4* w4 = (const float4*)(W + t * DIM);
  const float4* x4 = (const float4*)xr;
  float acc = b[t];
#pragma unroll 8
  for (int u = 0; u < DIM / 4; ++u) {
    float4 a = x4[u], w = w4[u];
    acc = fmaf(a.x, w.x, acc); acc = fmaf(a.y, w.y, acc);
    acc = fmaf(a.z, w.z, acc); acc = fmaf(a.w, w.w, acc);
  }
  float e = acc > 0.0f ? acc : expm1f(acc);
  float mu = blockReduceSum(e, red) * (1.0f / DIM);
  float d = e - mu;
  float var = blockReduceSum(d * d, red) * (1.0f / (DIM - 1));
  float denom = sqrtf(var) + LNEPS;
  out[row * DIM + t] = alpha[t] * d / denom + bias[t];
}

// ------- K3: q/k/v projections -------
__global__ void k_qkv(const float* __restrict__ xin,
                      const float* __restrict__ Wq, const float* __restrict__ bq,
                      const float* __restrict__ Wk, const float* __restrict__ bk,
                      const float* __restrict__ Wv, const float* __restrict__ bv,
                      float* __restrict__ q, float* __restrict__ k, float* __restrict__ v) {
  __shared__ float xr[256];
  int row = blockIdx.x, t = threadIdx.x;
  const float* W; const float* b; float* o;
  if (blockIdx.y == 0)      { W = Wq; b = bq; o = q; }
  else if (blockIdx.y == 1) { W = Wk; b = bk; o = k; }
  else                      { W = Wv; b = bv; o = v; }
  xr[t] = xin[row * DIM + t];
  __syncthreads();
  const float4* w4 = (const float4*)(W + t * DIM);
  const float4* x4 = (const float4*)xr;
  float acc = b[t];
#pragma unroll 8
  for (int u = 0; u < DIM / 4; ++u) {
    float4 a = x4[u], w = w4[u];
    acc = fmaf(a.x, w.x, acc); acc = fmaf(a.y, w.y, acc);
    acc = fmaf(a.z, w.z, acc); acc = fmaf(a.w, w.w, acc);
  }
  o[row * DIM + t] = acc;
}

// ------- K4: flash attention, 16-row strip per (strip, head); 4 rows/wave -------
__global__ __launch_bounds__(256, 3) void k_attn3(
    const float* __restrict__ q, const float* __restrict__ k,
    const float* __restrict__ v, const unsigned long long* __restrict__ maskbits,
    float* __restrict__ out) {
  __shared__ float kT[64 * 65];        // [d][c] padded: 16.6 KB
  __shared__ float v_l[64 * 64];       // [c][d]: 16 KB
  __shared__ float q_l[16 * 64];       // [r][d]: 4 KB
  __shared__ float p_l[16 * 64];       // [r][c]: 4 KB
  const float4* q_l4 = (const float4*)q_l;
  const float4* p_l4 = (const float4*)p_l;
  float4* v_l4 = (float4*)v_l;

  int h = blockIdx.y;
  int r0 = blockIdx.x * 16;
  int t = threadIdx.x;
  int wid = t >> 6, lane = t & 63;

  // load q strip (16 x 64)
  for (int i = t; i < 1024; i += 256) {
    int r = i >> 6, d = i & 63;
    q_l[r * 64 + d] = q[(size_t)(r0 + r) * DIM + h * HDK + d];
  }

  float o_acc[4], mreg[4], lreg[4], alph[4];
#pragma unroll
  for (int j = 0; j < 4; ++j) { o_acc[j] = 0.0f; mreg[j] = -3.0e38f; lreg[j] = 0.0f; }

  for (int mt = 0; mt < 64; ++mt) {
    int m0 = mt * 64;
    __syncthreads();   // previous tile fully consumed
    for (int i = t; i < 1024; i += 256) {
      int r = i >> 4, d4 = i & 15;
      float4 kv = *(const float4*)(k + (size_t)(m0 + r) * DIM + h * HDK + d4 * 4);
      kT[(d4 * 4 + 0) * 65 + r] = kv.x;
      kT[(d4 * 4 + 1) * 65 + r] = kv.y;
      kT[(d4 * 4 + 2) * 65 + r] = kv.z;
      kT[(d4 * 4 + 3) * 65 + r] = kv.w;
      v_l4[r * 16 + d4] = *(const float4*)(v + (size_t)(m0 + r) * DIM + h * HDK + d4 * 4);
    }
    __syncthreads();   // tiles ready

    // S = q . k^T for own 4 rows; lane = column within tile
    float accS[4];
#pragma unroll
    for (int j = 0; j < 4; ++j) accS[j] = 0.0f;
    for (int d4 = 0; d4 < 16; ++d4) {
      float k0 = kT[(d4 * 4 + 0) * 65 + lane];
      float k1 = kT[(d4 * 4 + 1) * 65 + lane];
      float k2 = kT[(d4 * 4 + 2) * 65 + lane];
      float k3 = kT[(d4 * 4 + 3) * 65 + lane];
#pragma unroll
      for (int j = 0; j < 4; ++j) {
        float4 q4 = q_l4[(wid * 4 + j) * 16 + d4];
        accS[j] = fmaf(q4.x, k0, fmaf(q4.y, k1, fmaf(q4.z, k2, fmaf(q4.w, k3, accS[j]))));
      }
    }
    // online softmax update per row (wave-local; mask via bit matrix)
#pragma unroll
    for (int j = 0; j < 4; ++j) {
      int r = wid * 4 + j;
      unsigned long long mb = maskbits[(size_t)(r0 + r) * 64 + mt];
      bool masked = (mb >> lane) & 1ull;
      float s = masked ? -1e9f : accS[j] * 0.125f;
      float tm = s;
      tm = fmaxf(tm, __shfl_xor(tm, 32));
      tm = fmaxf(tm, __shfl_xor(tm, 16));
      tm = fmaxf(tm, __shfl_xor(tm, 8));
      tm = fmaxf(tm, __shfl_xor(tm, 4));
      tm = fmaxf(tm, __shfl_xor(tm, 2));
      tm = fmaxf(tm, __shfl_xor(tm, 1));
      float m_new = fmaxf(mreg[j], tm);
      float p = expf(s - m_new);
      float ps = p;
      ps += __shfl_xor(ps, 32);
      ps += __shfl_xor(ps, 16);
      ps += __shfl_xor(ps, 8);
      ps += __shfl_xor(ps, 4);
      ps += __shfl_xor(ps, 2);
      ps += __shfl_xor(ps, 1);
      float a = expf(mreg[j] - m_new);
      lreg[j] = lreg[j] * a + ps;
      mreg[j] = m_new;
      alph[j] = a;
      p_l[r * 64 + lane] = p;
    }
    // PV accumulate (lane = d); p for own rows written by same wave
#pragma unroll
    for (int j = 0; j < 4; ++j) o_acc[j] *= alph[j];
    for (int c4 = 0; c4 < 16; ++c4) {
      float v0 = v_l[(c4 * 4 + 0) * 64 + lane];
      float v1 = v_l[(c4 * 4 + 1) * 64 + lane];
      float v2 = v_l[(c4 * 4 + 2) * 64 + lane];
      float v3 = v_l[(c4 * 4 + 3) * 64 + lane];
#pragma unroll
      for (int j = 0; j < 4; ++j) {
        float4 p4 = p_l4[(wid * 4 + j) * 16 + c4];
        o_acc[j] = fmaf(p4.x, v0, fmaf(p4.y, v1, fmaf(p4.z, v2, fmaf(p4.w, v3, o_acc[j]))));
      }
    }
  }
#pragma unroll
  for (int j = 0; j < 4; ++j) {
    int r = wid * 4 + j;
    out[(size_t)(r0 + r) * DIM + h * HDK + lane] = o_acc[j] / lreg[j];
  }
}

// ------- K5: x3 = LN(elu(att @ Wo^T + bo + x1)) -------
__global__ void k_out_ln(const float* __restrict__ att, const float* __restrict__ Wo,
                         const float* __restrict__ bo, const float* __restrict__ x1,
                         const float* __restrict__ alpha, const float* __restrict__ bias,
                         float* __restrict__ out) {
  __shared__ float xr[256];
  __shared__ float red[256];
  int row = blockIdx.x, t = threadIdx.x;
  xr[t] = att[row * DIM + t];
  __syncthreads();
  const float4* w4 = (const float4*)(Wo + t * DIM);
  const float4* x4 = (const float4*)xr;
  float acc = bo[t];
#pragma unroll 8
  for (int u = 0; u < DIM / 4; ++u) {
    float4 a = x4[u], w = w4[u];
    acc = fmaf(a.x, w.x, acc); acc = fmaf(a.y, w.y, acc);
    acc = fmaf(a.z, w.z, acc); acc = fmaf(a.w, w.w, acc);
  }
  float x2 = acc + x1[row * DIM + t];
  float e = x2 > 0.0f ? x2 : expm1f(x2);
  float mu = blockReduceSum(e, red) * (1.0f / DIM);
  float d = e - mu;
  float var = blockReduceSum(d * d, red) * (1.0f / (DIM - 1));
  float denom = sqrtf(var) + LNEPS;
  out[row * DIM + t] = alpha[t] * d / denom + bias[t];
}

// ------- K6a: build keT2[d2][c] = (x3[kidx[c]][2*d2], x3[kidx[c]][2*d2+1]) -------
__global__ void k_transpose_ke(const float* __restrict__ x3, const int* __restrict__ kidx,
                               float2* __restrict__ keT2) {
  __shared__ float tile[64 * 65];
  int cb = blockIdx.x, db = blockIdx.y;   // 64 x 4
  int t = threadIdx.x;
  for (int i = t; i < 4096; i += 256) {
    int ci = i >> 6, di = i & 63;
    int kj = kidx[cb * 64 + ci];
    tile[ci * 65 + di] = x3[(size_t)kj * DIM + db * 64 + di];
  }
  __syncthreads();
  for (int i = t; i < 2048; i += 256) {
    int di2 = i >> 6, ci = i & 63;   // di2 in 0..31
    keT2[(size_t)(db * 32 + di2) * NROWS + cb * 64 + ci] =
        make_float2(tile[ci * 65 + di2 * 2], tile[ci * 65 + di2 * 2 + 1]);
  }
}

// ------- K6b: 3-row strips: logits GEMM (LDS) -> rowsum -> softmax -> gumbel argmax -------
#define FR 3
__global__ __launch_bounds__(256) void k_final2(
    const float* __restrict__ x3, const float2* __restrict__ keT2,
    const int* __restrict__ qidx, float* __restrict__ outp) {
  __shared__ float  slog[FR * 4096];   // 48 KB
  __shared__ float2 sqe[FR * 128];     // 3 KB
  __shared__ double redd[256];
  __shared__ float  red[256];
  __shared__ int    redi[256];
  __shared__ float  redp[256];
  int r0 = blockIdx.x * FR;
  int nr = NROWS - r0; if (nr > FR) nr = FR;
  int t = threadIdx.x;
  for (int i = t; i < FR * 128; i += 256) {
    int j = i >> 7, d2 = i & 127;
    if (r0 + j < NROWS) {
      int qi = qidx[r0 + j];
      sqe[j * 128 + d2] = ((const float2*)(x3 + (size_t)qi * DIM))[d2];
    } else {
      sqe[j * 128 + d2] = make_float2(0.0f, 0.0f);
    }
  }
  __syncthreads();
  for (int c = t; c < NROWS; c += 256) {
    float a0 = 0.0f, a1 = 0.0f, a2 = 0.0f;
#pragma unroll 8
    for (int d2 = 0; d2 < 128; ++d2) {
      float2 kv = keT2[(size_t)d2 * NROWS + c];
      float2 q0 = sqe[0 * 128 + d2];
      float2 q1 = sqe[1 * 128 + d2];
      float2 q2 = sqe[2 * 128 + d2];
      a0 = fmaf(q0.x, kv.x, fmaf(q0.y, kv.y, a0));
      a1 = fmaf(q1.x, kv.x, fmaf(q1.y, kv.y, a1));
      a2 = fmaf(q2.x, kv.x, fmaf(q2.y, kv.y, a2));
    }
    slog[0 * 4096 + c] = a0;
    slog[1 * 4096 + c] = a1;
    slog[2 * 4096 + c] = a2;
  }
  __syncthreads();
  for (int j = 0; j < nr; ++j) {
    int row = r0 + j;
    float* sc = &slog[j * 4096];
    double part = 0.0;
    for (int c = t; c < NROWS; c += 256) part += (double)sc[c];
    double S = blockReduceSumD(part, redd);
    double inv = 1.0 / S;
    float lmax = -3.402823466e38f;
    for (int c = t; c < NROWS; c += 256) {
      float z = (float)((double)sc[c] * inv);
      sc[c] = z;
      lmax = fmaxf(lmax, z);
    }
    float M = blockReduceMax(lmax, red);
    double esum = 0.0;
    for (int c = t; c < NROWS; c += 256) {
      float p = expf(sc[c] - M);
      sc[c] = p;
      esum += (double)p;
    }
    float E = (float)blockReduceSumD(esum, redd);
    uint32_t rbase = (uint32_t)row * (uint32_t)NROWS;
    float best = -3.402823466e38f; int bidx = 0x7fffffff; float bp = 0.0f;
    for (int c = t; c < NROWS; c += 256) {
      uint32_t o0, o1;
      threefry2x32(0u, 42u, 0u, rbase + (uint32_t)c, o0, o1);
      uint32_t bits = o0 ^ o1;
      float u = jax_uniform_from_bits(bits);
      float g = -logf(-logf(u));
      float p = sc[c] / E;
      float val = p + g;
      if (val > best) { best = val; bidx = c; bp = p; }
    }
    red[t] = best; redi[t] = bidx; redp[t] = bp;
    __syncthreads();
    for (int s = 128; s > 0; s >>= 1) {
      if (t < s) {
        float vb = red[t + s];
        if (vb > red[t] || (vb == red[t] && redi[t + s] < redi[t])) {
          red[t] = vb; redi[t] = redi[t + s]; redp[t] = redp[t + s];
        }
      }
      __syncthreads();
    }
    if (t == 0) {
      outp[row]         = (float)redi[0];
      outp[NROWS + row] = redp[0];
    }
    __syncthreads();
  }
}

extern "C" void kernel_launch(void* const* d_in, const int* in_sizes, int n_in,
                              void* d_out, int out_size, void* d_ws, size_t ws_size,
                              hipStream_t stream) {
  const float* x_input = (const float*)d_in[0];
  const void*  mask    = (const void*)d_in[1];
  const int*   qidx    = (const int*)d_in[2];
  const int*   kidx    = (const int*)d_in[3];
  const float* alpha0  = (const float*)d_in[4];
  const float* bias0   = (const float*)d_in[5];
  const float* W1      = (const float*)d_in[6];
  const float* b1      = (const float*)d_in[7];
  const float* alpha1  = (const float*)d_in[8];
  const float* bias1   = (const float*)d_in[9];
  const float* alpha2  = (const float*)d_in[10];
  const float* bias2   = (const float*)d_in[11];
  const float* Wq = (const float*)d_in[12]; const float* bq = (const float*)d_in[13];
  const float* Wk = (const float*)d_in[14]; const float* bk = (const float*)d_in[15];
  const float* Wv = (const float*)d_in[16]; const float* bv = (const float*)d_in[17];
  const float* Wo = (const float*)d_in[18]; const float* bo = (const float*)d_in[19];

  float* ws = (float*)d_ws;
  const size_t MAT = (size_t)NROWS * DIM;  // 1M elements = 4MB
  float*  x0   = ws + 0 * MAT;             // dead after k_fc_elu_ln; reused for maskbits
  float*  x1   = ws + 1 * MAT;
  float*  q    = ws + 2 * MAT;
  float*  k    = ws + 3 * MAT;
  float*  v    = ws + 4 * MAT;
  float*  att  = ws + 5 * MAT;
  float*  x3   = ws + 6 * MAT;
  float2* keT2 = (float2*)(ws + 7 * MAT);  // 4 MB
  int*    mflag = (int*)(ws + 9 * MAT);
  unsigned long long* maskbits = (unsigned long long*)x0;  // 2 MB, reuses x0 slot
  float*  out = (float*)d_out;

  k_detect_mask<<<1, 256, 0, stream>>>((const uint32_t*)mask, mflag);
  k_ln0<<<NROWS, 256, 0, stream>>>(x_input, alpha0, bias0, x0);
  k_fc_elu_ln<<<NROWS, 256, 0, stream>>>(x0, W1, b1, alpha1, bias1, x1);
  // x0 is dead from here; pack mask bits into its slot
  k_mask_pack<<<NROWS, 256, 0, stream>>>(mask, mflag, maskbits);
  k_qkv<<<dim3(NROWS, 3), 256, 0, stream>>>(x1, Wq, bq, Wk, bk, Wv, bv, q, k, v);
  k_attn3<<<dim3(NROWS / 16, NHEAD), 256, 0, stream>>>(q, k, v, maskbits, att);
  k_out_ln<<<NROWS, 256, 0, stream>>>(att, Wo, bo, x1, alpha2, bias2, x3);
  k_transpose_ke<<<dim3(64, 4), 256, 0, stream>>>(x3, kidx, keT2);
  k_final2<<<(NROWS + FR - 1) / FR, 256, 0, stream>>>(x3, keT2, qidx, out);
}

// Round 10
// 1589.007 us; speedup vs baseline: 4.2080x; 1.3631x over previous
//
#include <hip/hip_runtime.h>
#include <hip/hip_bf16.h>
#include <stdint.h>
#include <math.h>

#define NROWS 4096
#define DIM   256
#define NHEAD 4
#define HDK   64
#define LNEPS 1e-6f
#define FLT_TINY 1.17549435e-38f

// ---------------- block reductions (256 threads) ----------------
__device__ __forceinline__ float blockReduceSum(float v, float* red) {
  int t = threadIdx.x;
  red[t] = v; __syncthreads();
  for (int s = 128; s > 0; s >>= 1) {
    if (t < s) red[t] += red[t + s];
    __syncthreads();
  }
  float r = red[0]; __syncthreads();
  return r;
}

__device__ __forceinline__ double blockReduceSumD(double v, double* red) {
  int t = threadIdx.x;
  red[t] = v; __syncthreads();
  for (int s = 128; s > 0; s >>= 1) {
    if (t < s) red[t] += red[t + s];
    __syncthreads();
  }
  double r = red[0]; __syncthreads();
  return r;
}

__device__ __forceinline__ float blockReduceMax(float v, float* red) {
  int t = threadIdx.x;
  red[t] = v; __syncthreads();
  for (int s = 128; s > 0; s >>= 1) {
    if (t < s) red[t] = fmaxf(red[t], red[t + s]);
    __syncthreads();
  }
  float r = red[0]; __syncthreads();
  return r;
}

// ------- JAX threefry2x32 (20 rounds) — KAT-verified -------
__device__ __forceinline__ uint32_t rotl32(uint32_t v, int d) {
  return (v << d) | (v >> (32 - d));
}

__device__ __forceinline__ void threefry2x32(uint32_t k0, uint32_t k1,
                                             uint32_t x0, uint32_t x1,
                                             uint32_t& o0, uint32_t& o1) {
  uint32_t ks0 = k0, ks1 = k1, ks2 = k0 ^ k1 ^ 0x1BD11BDAu;
  x0 += ks0; x1 += ks1;
#define TF_R(r) { x0 += x1; x1 = rotl32(x1, r); x1 ^= x0; }
  TF_R(13) TF_R(15) TF_R(26) TF_R(6)
  x0 += ks1; x1 += ks2 + 1u;
  TF_R(17) TF_R(29) TF_R(16) TF_R(24)
  x0 += ks2; x1 += ks0 + 2u;
  TF_R(13) TF_R(15) TF_R(26) TF_R(6)
  x0 += ks0; x1 += ks1 + 3u;
  TF_R(17) TF_R(29) TF_R(16) TF_R(24)
  x0 += ks1; x1 += ks2 + 4u;
  TF_R(13) TF_R(15) TF_R(26) TF_R(6)
  x0 += ks2; x1 += ks0 + 5u;
#undef TF_R
  o0 = x0; o1 = x1;
}

__device__ __forceinline__ float jax_uniform_from_bits(uint32_t bits) {
  uint32_t fb = (bits >> 9) | 0x3f800000u;
  float f = __uint_as_float(fb) - 1.0f;      // [0, 1)
  return fmaxf(FLT_TINY, f);
}

// ---------------- K0: detect mask dtype ----------------
// flag: 0=i32, 1=u8/bool, 2=f32, 3=bf16, 4=i64, 5=f64
__global__ void k_detect_mask(const uint32_t* __restrict__ m, int* __restrict__ flag) {
  __shared__ int s_u8, s_bf16, s_f32one, s_f64hi, s_ones, s_oddnz, s_other;
  int t = threadIdx.x;
  if (t == 0) { s_u8 = 0; s_bf16 = 0; s_f32one = 0; s_f64hi = 0; s_ones = 0; s_oddnz = 0; s_other = 0; }
  __syncthreads();
  int u8v = 0, bf16v = 0, f32v = 0, f64v = 0, onesv = 0, oddv = 0, otherv = 0;
  for (int i = t; i < 262144; i += 256) {
    uint32_t w = m[i];
    if (w == 0u) continue;
    if (i & 1) oddv = 1;
    if (w == 1u) { onesv = 1; continue; }
    uint32_t b0 = w & 0xFFu, b1 = (w >> 8) & 0xFFu;
    uint32_t b2 = (w >> 16) & 0xFFu, b3 = w >> 24;
    if (b0 <= 1u && b1 <= 1u && b2 <= 1u && b3 <= 1u) { u8v = 1; continue; }
    if (w == 0x3F800000u) { f32v = 1; continue; }
    if (w == 0x00003F80u || w == 0x3F803F80u) { bf16v = 1; continue; }
    if (w == 0x3FF00000u && (i & 1)) { f64v = 1; continue; }
    otherv = 1;
  }
  if (u8v) s_u8 = 1;
  if (bf16v) s_bf16 = 1;
  if (f32v) s_f32one = 1;
  if (f64v) s_f64hi = 1;
  if (onesv) s_ones = 1;
  if (oddv) s_oddnz = 1;
  if (otherv) s_other = 1;
  __syncthreads();
  if (t == 0) {
    int f;
    if (s_u8) f = 1;
    else if (s_bf16) f = 3;
    else if (s_f32one) f = 2;
    else if (s_f64hi && !s_ones) f = 5;
    else if (s_ones && !s_oddnz) f = 4;
    else f = 0;
    *flag = f;
  }
}

__device__ __forceinline__ bool mask_at(const void* mask, int mtype, size_t idx) {
  switch (mtype) {
    case 1:  return ((const uint8_t*)mask)[idx] != 0;
    case 0:  return ((const int*)mask)[idx] != 0;
    case 2:  return ((const float*)mask)[idx] != 0.0f;
    case 3:  return ((const uint16_t*)mask)[idx] != 0;
    case 4:  return ((const unsigned long long*)mask)[idx] != 0ull;
    default: return ((const unsigned long long*)mask)[idx] != 0ull;
  }
}

// ------- K0b: pack mask into bit matrix -------
__global__ __launch_bounds__(256) void k_mask_pack(const void* __restrict__ mask,
                                                   const int* __restrict__ mflag,
                                                   unsigned long long* __restrict__ bits) {
  int row = blockIdx.x, t = threadIdx.x;
  int wid = t >> 6, lane = t & 63;
  int mtype = *mflag;
  for (int it = 0; it < 16; ++it) {
    int w = it * 4 + wid;
    size_t idx = (size_t)row * NROWS + (size_t)w * 64 + lane;
    bool m = mask_at(mask, mtype, idx);
    unsigned long long b = __ballot(m);
    if (lane == 0) bits[(size_t)row * 64 + w] = b;
  }
}

// ---------------- K1: x0 = LN(x_input) ----------------
__global__ void k_ln0(const float* __restrict__ x, const float* __restrict__ alpha,
                      const float* __restrict__ bias, float* __restrict__ out) {
  __shared__ float red[256];
  int row = blockIdx.x, t = threadIdx.x;
  float v = x[row * DIM + t];
  float mu = blockReduceSum(v, red) * (1.0f / DIM);
  float d = v - mu;
  float var = blockReduceSum(d * d, red) * (1.0f / (DIM - 1));
  float denom = sqrtf(var) + LNEPS;
  out[row * DIM + t] = alpha[t] * d / denom + bias[t];
}

// ------- K2: x1 = LN(elu(x0 @ W1^T + b1)) -------
__global__ void k_fc_elu_ln(const float* __restrict__ xin, const float* __restrict__ W,
                            const float* __restrict__ b, const float* __restrict__ alpha,
                            const float* __restrict__ bias, float* __restrict__ out) {
  __shared__ float xr[256];
  __shared__ float red[256];
  int row = blockIdx.x, t = threadIdx.x;
  xr[t] = xin[row * DIM + t];
  __syncthreads();
  const float4* w4 = (const float4*)(W + t * DIM);
  const float4* x4 = (const float4*)xr;
  float acc = b[t];
#pragma unroll 8
  for (int u = 0; u < DIM / 4; ++u) {
    float4 a = x4[u], w = w4[u];
    acc = fmaf(a.x, w.x, acc); acc = fmaf(a.y, w.y, acc);
    acc = fmaf(a.z, w.z, acc); acc = fmaf(a.w, w.w, acc);
  }
  float e = acc > 0.0f ? acc : expm1f(acc);
  float mu = blockReduceSum(e, red) * (1.0f / DIM);
  float d = e - mu;
  float var = blockReduceSum(d * d, red) * (1.0f / (DIM - 1));
  float denom = sqrtf(var) + LNEPS;
  out[row * DIM + t] = alpha[t] * d / denom + bias[t];
}

// ------- K3: q/k/v projections, 8 rows per block (W streamed once per 8 rows) -------
#define QR 8
__global__ __launch_bounds__(256) void k_qkv2(
    const float* __restrict__ xin,
    const float* __restrict__ Wq, const float* __restrict__ bq,
    const float* __restrict__ Wk, const float* __restrict__ bk,
    const float* __restrict__ Wv, const float* __restrict__ bv,
    float* __restrict__ q, float* __restrict__ k, float* __restrict__ v) {
  __shared__ float xr[QR * 256];
  int row0 = blockIdx.x * QR, t = threadIdx.x;
  const float* W; const float* b; float* o;
  if (blockIdx.y == 0)      { W = Wq; b = bq; o = q; }
  else if (blockIdx.y == 1) { W = Wk; b = bk; o = k; }
  else                      { W = Wv; b = bv; o = v; }
  for (int i = t; i < QR * 256; i += 256)
    xr[i] = xin[(size_t)(row0 + (i >> 8)) * DIM + (i & 255)];
  __syncthreads();
  const float4* w4 = (const float4*)(W + t * DIM);
  const float4* x4 = (const float4*)xr;
  float acc[QR];
  float bb = b[t];
#pragma unroll
  for (int j = 0; j < QR; ++j) acc[j] = bb;
  for (int u = 0; u < DIM / 4; ++u) {
    float4 w = w4[u];
#pragma unroll
    for (int j = 0; j < QR; ++j) {
      float4 a = x4[j * 64 + u];
      acc[j] = fmaf(a.x, w.x, fmaf(a.y, w.y, fmaf(a.z, w.z, fmaf(a.w, w.w, acc[j]))));
    }
  }
#pragma unroll
  for (int j = 0; j < QR; ++j)
    o[(size_t)(row0 + j) * DIM + t] = acc[j];
}

// ------- K4: flash attention (no online max), XOR-swizzled kT, 40KB LDS -------
__global__ __launch_bounds__(256, 4) void k_attn4(
    const float* __restrict__ q, const float* __restrict__ k,
    const float* __restrict__ v, const unsigned long long* __restrict__ maskbits,
    float* __restrict__ out) {
  __shared__ float kT[64 * 64];        // [d][c xor-swizzled]: 16 KB
  __shared__ float v_l[64 * 64];       // [c][d]: 16 KB
  __shared__ float q_l[16 * 64];       // [r][d]: 4 KB
  __shared__ float p_l[16 * 64];       // [r][c]: 4 KB   (total 40960 B)
  const float4* q_l4 = (const float4*)q_l;
  const float4* p_l4 = (const float4*)p_l;
  float4* v_l4 = (float4*)v_l;

  int h = blockIdx.y;
  int r0 = blockIdx.x * 16;
  int t = threadIdx.x;
  int wid = t >> 6, lane = t & 63;

  for (int i = t; i < 1024; i += 256) {
    int r = i >> 6, d = i & 63;
    q_l[r * 64 + d] = q[(size_t)(r0 + r) * DIM + h * HDK + d];
  }

  float o_acc[4], lsum[4];
#pragma unroll
  for (int j = 0; j < 4; ++j) { o_acc[j] = 0.0f; lsum[j] = 0.0f; }

  for (int mt = 0; mt < 64; ++mt) {
    int m0 = mt * 64;
    __syncthreads();   // previous tile fully consumed
    for (int i = t; i < 1024; i += 256) {
      int r = i >> 4, d4 = i & 15;
      int swz = (4 * d4) & 31;
      float4 kv = *(const float4*)(k + (size_t)(m0 + r) * DIM + h * HDK + d4 * 4);
      int rs = r ^ swz;
      kT[(d4 * 4 + 0) * 64 + rs] = kv.x;
      kT[(d4 * 4 + 1) * 64 + rs] = kv.y;
      kT[(d4 * 4 + 2) * 64 + rs] = kv.z;
      kT[(d4 * 4 + 3) * 64 + rs] = kv.w;
      v_l4[r * 16 + d4] = *(const float4*)(v + (size_t)(m0 + r) * DIM + h * HDK + d4 * 4);
    }
    __syncthreads();   // tiles ready

    float accS[4];
#pragma unroll
    for (int j = 0; j < 4; ++j) accS[j] = 0.0f;
    for (int d4 = 0; d4 < 16; ++d4) {
      int ls = lane ^ ((4 * d4) & 31);
      float k0 = kT[(d4 * 4 + 0) * 64 + ls];
      float k1 = kT[(d4 * 4 + 1) * 64 + ls];
      float k2 = kT[(d4 * 4 + 2) * 64 + ls];
      float k3 = kT[(d4 * 4 + 3) * 64 + ls];
#pragma unroll
      for (int j = 0; j < 4; ++j) {
        float4 q4 = q_l4[(wid * 4 + j) * 16 + d4];
        accS[j] = fmaf(q4.x, k0, fmaf(q4.y, k1, fmaf(q4.z, k2, fmaf(q4.w, k3, accS[j]))));
      }
    }
    // p = exp(s) with fixed M=0 (scores bounded); masked -> 0; per-lane partial sums
#pragma unroll
    for (int j = 0; j < 4; ++j) {
      int r = wid * 4 + j;
      unsigned long long mb = maskbits[(size_t)(r0 + r) * 64 + mt];
      bool masked = (mb >> lane) & 1ull;
      float p = masked ? 0.0f : expf(accS[j] * 0.125f);
      lsum[j] += p;
      p_l[r * 64 + lane] = p;
    }
    // PV accumulate (lane = d); p for own rows written by same wave
    for (int c4 = 0; c4 < 16; ++c4) {
      float v0 = v_l[(c4 * 4 + 0) * 64 + lane];
      float v1 = v_l[(c4 * 4 + 1) * 64 + lane];
      float v2 = v_l[(c4 * 4 + 2) * 64 + lane];
      float v3 = v_l[(c4 * 4 + 3) * 64 + lane];
#pragma unroll
      for (int j = 0; j < 4; ++j) {
        float4 p4 = p_l4[(wid * 4 + j) * 16 + c4];
        o_acc[j] = fmaf(p4.x, v0, fmaf(p4.y, v1, fmaf(p4.z, v2, fmaf(p4.w, v3, o_acc[j]))));
      }
    }
  }
  // one reduction of lsum at the end (lsum lives in lane=col space)
#pragma unroll
  for (int j = 0; j < 4; ++j) {
    float s = lsum[j];
    s += __shfl_xor(s, 32); s += __shfl_xor(s, 16); s += __shfl_xor(s, 8);
    s += __shfl_xor(s, 4);  s += __shfl_xor(s, 2);  s += __shfl_xor(s, 1);
    int r = wid * 4 + j;
    out[(size_t)(r0 + r) * DIM + h * HDK + lane] = o_acc[j] / s;
  }
}

// ------- K5: x3 = LN(elu(att @ Wo^T + bo + x1)) -------
__global__ void k_out_ln(const float* __restrict__ att, const float* __restrict__ Wo,
                         const float* __restrict__ bo, const float* __restrict__ x1,
                         const float* __restrict__ alpha, const float* __restrict__ bias,
                         float* __restrict__ out) {
  __shared__ float xr[256];
  __shared__ float red[256];
  int row = blockIdx.x, t = threadIdx.x;
  xr[t] = att[row * DIM + t];
  __syncthreads();
  const float4* w4 = (const float4*)(Wo + t * DIM);
  const float4* x4 = (const float4*)xr;
  float acc = bo[t];
#pragma unroll 8
  for (int u = 0; u < DIM / 4; ++u) {
    float4 a = x4[u], w = w4[u];
    acc = fmaf(a.x, w.x, acc); acc = fmaf(a.y, w.y, acc);
    acc = fmaf(a.z, w.z, acc); acc = fmaf(a.w, w.w, acc);
  }
  float x2 = acc + x1[row * DIM + t];
  float e = x2 > 0.0f ? x2 : expm1f(x2);
  float mu = blockReduceSum(e, red) * (1.0f / DIM);
  float d = e - mu;
  float var = blockReduceSum(d * d, red) * (1.0f / (DIM - 1));
  float denom = sqrtf(var) + LNEPS;
  out[row * DIM + t] = alpha[t] * d / denom + bias[t];
}

// ------- K6-fast-a: logits GEMM, 64x64 tiles: logits[r][c] = x3[qidx[r]] . x3[kidx[c]] -------
__global__ __launch_bounds__(256) void k_logits(
    const float* __restrict__ x3, const int* __restrict__ qidx,
    const int* __restrict__ kidx, float* __restrict__ logits) {
  __shared__ float At[64 * 65];   // [row][k] pad 65
  __shared__ float Bt[64 * 65];
  int c0 = blockIdx.x * 64, r0 = blockIdx.y * 64;
  int t = threadIdx.x;
  int tr = t >> 4, tc = t & 15;
  float acc[4][4];
#pragma unroll
  for (int i = 0; i < 4; ++i)
#pragma unroll
    for (int j = 0; j < 4; ++j) acc[i][j] = 0.0f;

  for (int kc = 0; kc < 4; ++kc) {
    int k0 = kc * 64;
    __syncthreads();
    for (int i = t; i < 1024; i += 256) {
      int row = i >> 4, k4 = i & 15;
      float4 av = *(const float4*)(x3 + (size_t)qidx[r0 + row] * DIM + k0 + k4 * 4);
      float4 bv = *(const float4*)(x3 + (size_t)kidx[c0 + row] * DIM + k0 + k4 * 4);
      At[row * 65 + k4 * 4 + 0] = av.x; At[row * 65 + k4 * 4 + 1] = av.y;
      At[row * 65 + k4 * 4 + 2] = av.z; At[row * 65 + k4 * 4 + 3] = av.w;
      Bt[row * 65 + k4 * 4 + 0] = bv.x; Bt[row * 65 + k4 * 4 + 1] = bv.y;
      Bt[row * 65 + k4 * 4 + 2] = bv.z; Bt[row * 65 + k4 * 4 + 3] = bv.w;
    }
    __syncthreads();
#pragma unroll 4
    for (int kk = 0; kk < 64; ++kk) {
      float a0 = At[(tr * 4 + 0) * 65 + kk];
      float a1 = At[(tr * 4 + 1) * 65 + kk];
      float a2 = At[(tr * 4 + 2) * 65 + kk];
      float a3 = At[(tr * 4 + 3) * 65 + kk];
      float b0 = Bt[(tc * 4 + 0) * 65 + kk];
      float b1 = Bt[(tc * 4 + 1) * 65 + kk];
      float b2 = Bt[(tc * 4 + 2) * 65 + kk];
      float b3 = Bt[(tc * 4 + 3) * 65 + kk];
      acc[0][0] = fmaf(a0, b0, acc[0][0]); acc[0][1] = fmaf(a0, b1, acc[0][1]);
      acc[0][2] = fmaf(a0, b2, acc[0][2]); acc[0][3] = fmaf(a0, b3, acc[0][3]);
      acc[1][0] = fmaf(a1, b0, acc[1][0]); acc[1][1] = fmaf(a1, b1, acc[1][1]);
      acc[1][2] = fmaf(a1, b2, acc[1][2]); acc[1][3] = fmaf(a1, b3, acc[1][3]);
      acc[2][0] = fmaf(a2, b0, acc[2][0]); acc[2][1] = fmaf(a2, b1, acc[2][1]);
      acc[2][2] = fmaf(a2, b2, acc[2][2]); acc[2][3] = fmaf(a2, b3, acc[2][3]);
      acc[3][0] = fmaf(a3, b0, acc[3][0]); acc[3][1] = fmaf(a3, b1, acc[3][1]);
      acc[3][2] = fmaf(a3, b2, acc[3][2]); acc[3][3] = fmaf(a3, b3, acc[3][3]);
    }
  }
#pragma unroll
  for (int i = 0; i < 4; ++i) {
    float4 o = make_float4(acc[i][0], acc[i][1], acc[i][2], acc[i][3]);
    *(float4*)(logits + (size_t)(r0 + tr * 4 + i) * NROWS + c0 + tc * 4) = o;
  }
}

// ------- K6-fast-b: per-row finalize from materialized logits -------
__global__ __launch_bounds__(256) void k_final3(
    const float* __restrict__ logits, float* __restrict__ outp) {
  __shared__ float  sc[4096];
  __shared__ double redd[256];
  __shared__ float  red[256];
  __shared__ int    redi[256];
  __shared__ float  redp[256];
  int row = blockIdx.x, t = threadIdx.x;
  for (int c = t; c < NROWS; c += 256) sc[c] = logits[(size_t)row * NROWS + c];
  __syncthreads();
  double part = 0.0;
  for (int c = t; c < NROWS; c += 256) part += (double)sc[c];
  double S = blockReduceSumD(part, redd);
  double inv = 1.0 / S;
  float lmax = -3.402823466e38f;
  for (int c = t; c < NROWS; c += 256) {
    float z = (float)((double)sc[c] * inv);
    sc[c] = z;
    lmax = fmaxf(lmax, z);
  }
  float M = blockReduceMax(lmax, red);
  double esum = 0.0;
  for (int c = t; c < NROWS; c += 256) {
    float p = expf(sc[c] - M);
    sc[c] = p;
    esum += (double)p;
  }
  float E = (float)blockReduceSumD(esum, redd);
  uint32_t rbase = (uint32_t)row * (uint32_t)NROWS;
  float best = -3.402823466e38f; int bidx = 0x7fffffff; float bp = 0.0f;
  for (int c = t; c < NROWS; c += 256) {
    uint32_t o0, o1;
    threefry2x32(0u, 42u, 0u, rbase + (uint32_t)c, o0, o1);
    uint32_t bits = o0 ^ o1;
    float u = jax_uniform_from_bits(bits);
    float g = -logf(-logf(u));
    float p = sc[c] / E;
    float val = p + g;
    if (val > best) { best = val; bidx = c; bp = p; }
  }
  red[t] = best; redi[t] = bidx; redp[t] = bp;
  __syncthreads();
  for (int s = 128; s > 0; s >>= 1) {
    if (t < s) {
      float vb = red[t + s];
      if (vb > red[t] || (vb == red[t] && redi[t + s] < redi[t])) {
        red[t] = vb; redi[t] = redi[t + s]; redp[t] = redp[t + s];
      }
    }
    __syncthreads();
  }
  if (t == 0) {
    outp[row]         = (float)redi[0];
    outp[NROWS + row] = redp[0];
  }
}

// ------- fallback path kernels (proven round 8/9) -------
__global__ void k_transpose_ke(const float* __restrict__ x3, const int* __restrict__ kidx,
                               float2* __restrict__ keT2) {
  __shared__ float tile[64 * 65];
  int cb = blockIdx.x, db = blockIdx.y;
  int t = threadIdx.x;
  for (int i = t; i < 4096; i += 256) {
    int ci = i >> 6, di = i & 63;
    int kj = kidx[cb * 64 + ci];
    tile[ci * 65 + di] = x3[(size_t)kj * DIM + db * 64 + di];
  }
  __syncthreads();
  for (int i = t; i < 2048; i += 256) {
    int di2 = i >> 6, ci = i & 63;
    keT2[(size_t)(db * 32 + di2) * NROWS + cb * 64 + ci] =
        make_float2(tile[ci * 65 + di2 * 2], tile[ci * 65 + di2 * 2 + 1]);
  }
}

#define FR 3
__global__ __launch_bounds__(256) void k_final2(
    const float* __restrict__ x3, const float2* __restrict__ keT2,
    const int* __restrict__ qidx, float* __restrict__ outp) {
  __shared__ float  slog[FR * 4096];
  __shared__ float2 sqe[FR * 128];
  __shared__ double redd[256];
  __shared__ float  red[256];
  __shared__ int    redi[256];
  __shared__ float  redp[256];
  int r0 = blockIdx.x * FR;
  int nr = NROWS - r0; if (nr > FR) nr = FR;
  int t = threadIdx.x;
  for (int i = t; i < FR * 128; i += 256) {
    int j = i >> 7, d2 = i & 127;
    if (r0 + j < NROWS) {
      int qi = qidx[r0 + j];
      sqe[j * 128 + d2] = ((const float2*)(x3 + (size_t)qi * DIM))[d2];
    } else {
      sqe[j * 128 + d2] = make_float2(0.0f, 0.0f);
    }
  }
  __syncthreads();
  for (int c = t; c < NROWS; c += 256) {
    float a0 = 0.0f, a1 = 0.0f, a2 = 0.0f;
#pragma unroll 8
    for (int d2 = 0; d2 < 128; ++d2) {
      float2 kv = keT2[(size_t)d2 * NROWS + c];
      float2 q0 = sqe[0 * 128 + d2];
      float2 q1 = sqe[1 * 128 + d2];
      float2 q2 = sqe[2 * 128 + d2];
      a0 = fmaf(q0.x, kv.x, fmaf(q0.y, kv.y, a0));
      a1 = fmaf(q1.x, kv.x, fmaf(q1.y, kv.y, a1));
      a2 = fmaf(q2.x, kv.x, fmaf(q2.y, kv.y, a2));
    }
    slog[0 * 4096 + c] = a0;
    slog[1 * 4096 + c] = a1;
    slog[2 * 4096 + c] = a2;
  }
  __syncthreads();
  for (int j = 0; j < nr; ++j) {
    int row = r0 + j;
    float* sc = &slog[j * 4096];
    double part = 0.0;
    for (int c = t; c < NROWS; c += 256) part += (double)sc[c];
    double S = blockReduceSumD(part, redd);
    double inv = 1.0 / S;
    float lmax = -3.402823466e38f;
    for (int c = t; c < NROWS; c += 256) {
      float z = (float)((double)sc[c] * inv);
      sc[c] = z;
      lmax = fmaxf(lmax, z);
    }
    float M = blockReduceMax(lmax, red);
    double esum = 0.0;
    for (int c = t; c < NROWS; c += 256) {
      float p = expf(sc[c] - M);
      sc[c] = p;
      esum += (double)p;
    }
    float E = (float)blockReduceSumD(esum, redd);
    uint32_t rbase = (uint32_t)row * (uint32_t)NROWS;
    float best = -3.402823466e38f; int bidx = 0x7fffffff; float bp = 0.0f;
    for (int c = t; c < NROWS; c += 256) {
      uint32_t o0, o1;
      threefry2x32(0u, 42u, 0u, rbase + (uint32_t)c, o0, o1);
      uint32_t bits = o0 ^ o1;
      float u = jax_uniform_from_bits(bits);
      float g = -logf(-logf(u));
      float p = sc[c] / E;
      float val = p + g;
      if (val > best) { best = val; bidx = c; bp = p; }
    }
    red[t] = best; redi[t] = bidx; redp[t] = bp;
    __syncthreads();
    for (int s = 128; s > 0; s >>= 1) {
      if (t < s) {
        float vb = red[t + s];
        if (vb > red[t] || (vb == red[t] && redi[t + s] < redi[t])) {
          red[t] = vb; redi[t] = redi[t + s]; redp[t] = redp[t + s];
        }
      }
      __syncthreads();
    }
    if (t == 0) {
      outp[row]         = (float)redi[0];
      outp[NROWS + row] = redp[0];
    }
    __syncthreads();
  }
}

extern "C" void kernel_launch(void* const* d_in, const int* in_sizes, int n_in,
                              void* d_out, int out_size, void* d_ws, size_t ws_size,
                              hipStream_t stream) {
  const float* x_input = (const float*)d_in[0];
  const void*  mask    = (const void*)d_in[1];
  const int*   qidx    = (const int*)d_in[2];
  const int*   kidx    = (const int*)d_in[3];
  const float* alpha0  = (const float*)d_in[4];
  const float* bias0   = (const float*)d_in[5];
  const float* W1      = (const float*)d_in[6];
  const float* b1      = (const float*)d_in[7];
  const float* alpha1  = (const float*)d_in[8];
  const float* bias1   = (const float*)d_in[9];
  const float* alpha2  = (const float*)d_in[10];
  const float* bias2   = (const float*)d_in[11];
  const float* Wq = (const float*)d_in[12]; const float* bq = (const float*)d_in[13];
  const float* Wk = (const float*)d_in[14]; const float* bk = (const float*)d_in[15];
  const float* Wv = (const float*)d_in[16]; const float* bv = (const float*)d_in[17];
  const float* Wo = (const float*)d_in[18]; const float* bo = (const float*)d_in[19];

  float* ws = (float*)d_ws;
  const size_t MAT  = (size_t)NROWS * DIM;        // 1M floats
  const size_t MATB = MAT * sizeof(float);        // 4 MB
  float*  x0   = ws + 0 * MAT;   // reused as maskbits after k_fc_elu_ln
  float*  x1   = ws + 1 * MAT;
  float*  q    = ws + 2 * MAT;
  float*  k    = ws + 3 * MAT;
  float*  v    = ws + 4 * MAT;
  float*  att  = ws + 5 * MAT;
  float*  x3   = ws + 6 * MAT;
  unsigned long long* maskbits = (unsigned long long*)x0;
  float*  out = (float*)d_out;

  bool fast = ws_size >= 23ull * MATB + 4096ull;
  // fast layout: logits at 7*MAT (16 MAT = 67MB), mflag at 23*MAT
  // fallback layout: keT2 at 7*MAT (2 MAT), mflag at 9*MAT
  float*  logits = ws + 7 * MAT;
  float2* keT2   = (float2*)(ws + 7 * MAT);
  int* mflag = fast ? (int*)(ws + 23 * MAT) : (int*)(ws + 9 * MAT);

  k_detect_mask<<<1, 256, 0, stream>>>((const uint32_t*)mask, mflag);
  k_ln0<<<NROWS, 256, 0, stream>>>(x_input, alpha0, bias0, x0);
  k_fc_elu_ln<<<NROWS, 256, 0, stream>>>(x0, W1, b1, alpha1, bias1, x1);
  // x0 dead; pack mask bits into its slot
  k_mask_pack<<<NROWS, 256, 0, stream>>>(mask, mflag, maskbits);
  k_qkv2<<<dim3(NROWS / QR, 3), 256, 0, stream>>>(x1, Wq, bq, Wk, bk, Wv, bv, q, k, v);
  k_attn4<<<dim3(NROWS / 16, NHEAD), 256, 0, stream>>>(q, k, v, maskbits, att);
  k_out_ln<<<NROWS, 256, 0, stream>>>(att, Wo, bo, x1, alpha2, bias2, x3);
  if (fast) {
    k_logits<<<dim3(NROWS / 64, NROWS / 64), 256, 0, stream>>>(x3, qidx, kidx, logits);
    k_final3<<<NROWS, 256, 0, stream>>>(logits, out);
  } else {
    k_transpose_ke<<<dim3(64, 4), 256, 0, stream>>>(x3, kidx, keT2);
    k_final2<<<(NROWS + FR - 1) / FR, 256, 0, stream>>>(x3, keT2, qidx, out);
  }
}

// Round 11
// 1526.156 us; speedup vs baseline: 4.3813x; 1.0412x over previous
//
#include <hip/hip_runtime.h>
#include <hip/hip_bf16.h>
#include <stdint.h>
#include <math.h>

#define NROWS 4096
#define DIM   256
#define NHEAD 4
#define HDK   64
#define LNEPS 1e-6f
#define FLT_TINY 1.17549435e-38f

// ---------------- block reductions (256 threads) ----------------
__device__ __forceinline__ float blockReduceSum(float v, float* red) {
  int t = threadIdx.x;
  red[t] = v; __syncthreads();
  for (int s = 128; s > 0; s >>= 1) {
    if (t < s) red[t] += red[t + s];
    __syncthreads();
  }
  float r = red[0]; __syncthreads();
  return r;
}

__device__ __forceinline__ double blockReduceSumD(double v, double* red) {
  int t = threadIdx.x;
  red[t] = v; __syncthreads();
  for (int s = 128; s > 0; s >>= 1) {
    if (t < s) red[t] += red[t + s];
    __syncthreads();
  }
  double r = red[0]; __syncthreads();
  return r;
}

__device__ __forceinline__ float blockReduceMax(float v, float* red) {
  int t = threadIdx.x;
  red[t] = v; __syncthreads();
  for (int s = 128; s > 0; s >>= 1) {
    if (t < s) red[t] = fmaxf(red[t], red[t + s]);
    __syncthreads();
  }
  float r = red[0]; __syncthreads();
  return r;
}

// ------- JAX threefry2x32 (20 rounds) — KAT-verified -------
__device__ __forceinline__ uint32_t rotl32(uint32_t v, int d) {
  return (v << d) | (v >> (32 - d));
}

__device__ __forceinline__ void threefry2x32(uint32_t k0, uint32_t k1,
                                             uint32_t x0, uint32_t x1,
                                             uint32_t& o0, uint32_t& o1) {
  uint32_t ks0 = k0, ks1 = k1, ks2 = k0 ^ k1 ^ 0x1BD11BDAu;
  x0 += ks0; x1 += ks1;
#define TF_R(r) { x0 += x1; x1 = rotl32(x1, r); x1 ^= x0; }
  TF_R(13) TF_R(15) TF_R(26) TF_R(6)
  x0 += ks1; x1 += ks2 + 1u;
  TF_R(17) TF_R(29) TF_R(16) TF_R(24)
  x0 += ks2; x1 += ks0 + 2u;
  TF_R(13) TF_R(15) TF_R(26) TF_R(6)
  x0 += ks0; x1 += ks1 + 3u;
  TF_R(17) TF_R(29) TF_R(16) TF_R(24)
  x0 += ks1; x1 += ks2 + 4u;
  TF_R(13) TF_R(15) TF_R(26) TF_R(6)
  x0 += ks2; x1 += ks0 + 5u;
#undef TF_R
  o0 = x0; o1 = x1;
}

__device__ __forceinline__ float jax_uniform_from_bits(uint32_t bits) {
  uint32_t fb = (bits >> 9) | 0x3f800000u;
  float f = __uint_as_float(fb) - 1.0f;      // [0, 1)
  return fmaxf(FLT_TINY, f);
}

// ---------------- K0: detect mask dtype ----------------
// flag: 0=i32, 1=u8/bool, 2=f32, 3=bf16, 4=i64, 5=f64
__global__ void k_detect_mask(const uint32_t* __restrict__ m, int* __restrict__ flag) {
  __shared__ int s_u8, s_bf16, s_f32one, s_f64hi, s_ones, s_oddnz, s_other;
  int t = threadIdx.x;
  if (t == 0) { s_u8 = 0; s_bf16 = 0; s_f32one = 0; s_f64hi = 0; s_ones = 0; s_oddnz = 0; s_other = 0; }
  __syncthreads();
  int u8v = 0, bf16v = 0, f32v = 0, f64v = 0, onesv = 0, oddv = 0, otherv = 0;
  for (int i = t; i < 262144; i += 256) {
    uint32_t w = m[i];
    if (w == 0u) continue;
    if (i & 1) oddv = 1;
    if (w == 1u) { onesv = 1; continue; }
    uint32_t b0 = w & 0xFFu, b1 = (w >> 8) & 0xFFu;
    uint32_t b2 = (w >> 16) & 0xFFu, b3 = w >> 24;
    if (b0 <= 1u && b1 <= 1u && b2 <= 1u && b3 <= 1u) { u8v = 1; continue; }
    if (w == 0x3F800000u) { f32v = 1; continue; }
    if (w == 0x00003F80u || w == 0x3F803F80u) { bf16v = 1; continue; }
    if (w == 0x3FF00000u && (i & 1)) { f64v = 1; continue; }
    otherv = 1;
  }
  if (u8v) s_u8 = 1;
  if (bf16v) s_bf16 = 1;
  if (f32v) s_f32one = 1;
  if (f64v) s_f64hi = 1;
  if (onesv) s_ones = 1;
  if (oddv) s_oddnz = 1;
  if (otherv) s_other = 1;
  __syncthreads();
  if (t == 0) {
    int f;
    if (s_u8) f = 1;
    else if (s_bf16) f = 3;
    else if (s_f32one) f = 2;
    else if (s_f64hi && !s_ones) f = 5;
    else if (s_ones && !s_oddnz) f = 4;
    else f = 0;
    *flag = f;
  }
}

__device__ __forceinline__ bool mask_at(const void* mask, int mtype, size_t idx) {
  switch (mtype) {
    case 1:  return ((const uint8_t*)mask)[idx] != 0;
    case 0:  return ((const int*)mask)[idx] != 0;
    case 2:  return ((const float*)mask)[idx] != 0.0f;
    case 3:  return ((const uint16_t*)mask)[idx] != 0;
    case 4:  return ((const unsigned long long*)mask)[idx] != 0ull;
    default: return ((const unsigned long long*)mask)[idx] != 0ull;
  }
}

// ------- K0b: pack mask into bit matrix -------
__global__ __launch_bounds__(256) void k_mask_pack(const void* __restrict__ mask,
                                                   const int* __restrict__ mflag,
                                                   unsigned long long* __restrict__ bits) {
  int row = blockIdx.x, t = threadIdx.x;
  int wid = t >> 6, lane = t & 63;
  int mtype = *mflag;
  for (int it = 0; it < 16; ++it) {
    int w = it * 4 + wid;
    size_t idx = (size_t)row * NROWS + (size_t)w * 64 + lane;
    bool m = mask_at(mask, mtype, idx);
    unsigned long long b = __ballot(m);
    if (lane == 0) bits[(size_t)row * 64 + w] = b;
  }
}

// ------- K1+K2 fused: x1 = LN(elu(LN(x_input) @ W1^T + b1)) -------
__global__ __launch_bounds__(256) void k_ln_fc_elu_ln(
    const float* __restrict__ xin, const float* __restrict__ alpha0,
    const float* __restrict__ bias0, const float* __restrict__ W,
    const float* __restrict__ b, const float* __restrict__ alpha,
    const float* __restrict__ bias, float* __restrict__ out) {
  __shared__ float xr[256];
  __shared__ float red[256];
  int row = blockIdx.x, t = threadIdx.x;
  // LN0 inline
  float vx = xin[row * DIM + t];
  float mu0 = blockReduceSum(vx, red) * (1.0f / DIM);
  float d0 = vx - mu0;
  float var0 = blockReduceSum(d0 * d0, red) * (1.0f / (DIM - 1));
  float den0 = sqrtf(var0) + LNEPS;
  xr[t] = alpha0[t] * d0 / den0 + bias0[t];
  __syncthreads();
  // FC + elu + LN1
  const float4* w4 = (const float4*)(W + t * DIM);
  const float4* x4 = (const float4*)xr;
  float acc = b[t];
#pragma unroll 8
  for (int u = 0; u < DIM / 4; ++u) {
    float4 a = x4[u], w = w4[u];
    acc = fmaf(a.x, w.x, acc); acc = fmaf(a.y, w.y, acc);
    acc = fmaf(a.z, w.z, acc); acc = fmaf(a.w, w.w, acc);
  }
  float e = acc > 0.0f ? acc : expm1f(acc);
  float mu = blockReduceSum(e, red) * (1.0f / DIM);
  float d = e - mu;
  float var = blockReduceSum(d * d, red) * (1.0f / (DIM - 1));
  float denom = sqrtf(var) + LNEPS;
  out[row * DIM + t] = alpha[t] * d / denom + bias[t];
}

// ------- K3: q/k/v projections, 8 rows per block -------
#define QR 8
__global__ __launch_bounds__(256) void k_qkv2(
    const float* __restrict__ xin,
    const float* __restrict__ Wq, const float* __restrict__ bq,
    const float* __restrict__ Wk, const float* __restrict__ bk,
    const float* __restrict__ Wv, const float* __restrict__ bv,
    float* __restrict__ q, float* __restrict__ k, float* __restrict__ v) {
  __shared__ float xr[QR * 256];
  int row0 = blockIdx.x * QR, t = threadIdx.x;
  const float* W; const float* b; float* o;
  if (blockIdx.y == 0)      { W = Wq; b = bq; o = q; }
  else if (blockIdx.y == 1) { W = Wk; b = bk; o = k; }
  else                      { W = Wv; b = bv; o = v; }
  for (int i = t; i < QR * 256; i += 256)
    xr[i] = xin[(size_t)(row0 + (i >> 8)) * DIM + (i & 255)];
  __syncthreads();
  const float4* w4 = (const float4*)(W + t * DIM);
  const float4* x4 = (const float4*)xr;
  float acc[QR];
  float bb = b[t];
#pragma unroll
  for (int j = 0; j < QR; ++j) acc[j] = bb;
  for (int u = 0; u < DIM / 4; ++u) {
    float4 w = w4[u];
#pragma unroll
    for (int j = 0; j < QR; ++j) {
      float4 a = x4[j * 64 + u];
      acc[j] = fmaf(a.x, w.x, fmaf(a.y, w.y, fmaf(a.z, w.z, fmaf(a.w, w.w, acc[j]))));
    }
  }
#pragma unroll
  for (int j = 0; j < QR; ++j)
    o[(size_t)(row0 + j) * DIM + t] = acc[j];
}

// ------- K4: flash attention; kT as float4 slots with XOR slot-swizzle -------
__global__ __launch_bounds__(256, 4) void k_attn5(
    const float* __restrict__ q, const float* __restrict__ k,
    const float* __restrict__ v, const unsigned long long* __restrict__ maskbits,
    float* __restrict__ out) {
  __shared__ float4 kT4[16 * 64];      // slot (d4, c): k[c][4d4..+3]; idx d4*64 + (c ^ (4*d4 & 63)); 16 KB
  __shared__ float v_l[64 * 64];       // [c][d]: 16 KB
  __shared__ float q_l[16 * 64];       // [r][d]: 4 KB
  __shared__ float p_l[16 * 64];       // [r][c]: 4 KB   (total 40960 B)
  const float4* q_l4 = (const float4*)q_l;
  const float4* p_l4 = (const float4*)p_l;
  float4* v_l4 = (float4*)v_l;

  int h = blockIdx.y;
  int r0 = blockIdx.x * 16;
  int t = threadIdx.x;
  int wid = t >> 6, lane = t & 63;

  for (int i = t; i < 1024; i += 256) {
    int r = i >> 6, d = i & 63;
    q_l[r * 64 + d] = q[(size_t)(r0 + r) * DIM + h * HDK + d];
  }

  float o_acc[4], lsum[4];
#pragma unroll
  for (int j = 0; j < 4; ++j) { o_acc[j] = 0.0f; lsum[j] = 0.0f; }

  for (int mt = 0; mt < 64; ++mt) {
    int m0 = mt * 64;
    __syncthreads();   // previous tile fully consumed
    for (int i = t; i < 1024; i += 256) {
      int r = i >> 4, d4 = i & 15;
      float4 kv = *(const float4*)(k + (size_t)(m0 + r) * DIM + h * HDK + d4 * 4);
      kT4[d4 * 64 + (r ^ ((d4 * 4) & 63))] = kv;        // b128 write, conflict-free
      v_l4[r * 16 + d4] = *(const float4*)(v + (size_t)(m0 + r) * DIM + h * HDK + d4 * 4);
    }
    __syncthreads();   // tiles ready

    float accS[4];
#pragma unroll
    for (int j = 0; j < 4; ++j) accS[j] = 0.0f;
    for (int d4 = 0; d4 < 16; ++d4) {
      float4 kv = kT4[d4 * 64 + (lane ^ ((d4 * 4) & 63))];  // b128 read, conflict-free
#pragma unroll
      for (int j = 0; j < 4; ++j) {
        float4 q4 = q_l4[(wid * 4 + j) * 16 + d4];
        accS[j] = fmaf(q4.x, kv.x, fmaf(q4.y, kv.y, fmaf(q4.z, kv.z, fmaf(q4.w, kv.w, accS[j]))));
      }
    }
    // p = exp(s) with fixed M=0 (scores bounded); masked -> 0
#pragma unroll
    for (int j = 0; j < 4; ++j) {
      int r = wid * 4 + j;
      unsigned long long mb = maskbits[(size_t)(r0 + r) * 64 + mt];
      bool masked = (mb >> lane) & 1ull;
      float p = masked ? 0.0f : expf(accS[j] * 0.125f);
      lsum[j] += p;
      p_l[r * 64 + lane] = p;
    }
    // PV accumulate (lane = d)
    for (int c4 = 0; c4 < 16; ++c4) {
      float v0 = v_l[(c4 * 4 + 0) * 64 + lane];
      float v1 = v_l[(c4 * 4 + 1) * 64 + lane];
      float v2 = v_l[(c4 * 4 + 2) * 64 + lane];
      float v3 = v_l[(c4 * 4 + 3) * 64 + lane];
#pragma unroll
      for (int j = 0; j < 4; ++j) {
        float4 p4 = p_l4[(wid * 4 + j) * 16 + c4];
        o_acc[j] = fmaf(p4.x, v0, fmaf(p4.y, v1, fmaf(p4.z, v2, fmaf(p4.w, v3, o_acc[j]))));
      }
    }
  }
#pragma unroll
  for (int j = 0; j < 4; ++j) {
    float s = lsum[j];
    s += __shfl_xor(s, 32); s += __shfl_xor(s, 16); s += __shfl_xor(s, 8);
    s += __shfl_xor(s, 4);  s += __shfl_xor(s, 2);  s += __shfl_xor(s, 1);
    int r = wid * 4 + j;
    out[(size_t)(r0 + r) * DIM + h * HDK + lane] = o_acc[j] / s;
  }
}

// ------- K5: x3 = LN(elu(att @ Wo^T + bo + x1)) -------
__global__ void k_out_ln(const float* __restrict__ att, const float* __restrict__ Wo,
                         const float* __restrict__ bo, const float* __restrict__ x1,
                         const float* __restrict__ alpha, const float* __restrict__ bias,
                         float* __restrict__ out) {
  __shared__ float xr[256];
  __shared__ float red[256];
  int row = blockIdx.x, t = threadIdx.x;
  xr[t] = att[row * DIM + t];
  __syncthreads();
  const float4* w4 = (const float4*)(Wo + t * DIM);
  const float4* x4 = (const float4*)xr;
  float acc = bo[t];
#pragma unroll 8
  for (int u = 0; u < DIM / 4; ++u) {
    float4 a = x4[u], w = w4[u];
    acc = fmaf(a.x, w.x, acc); acc = fmaf(a.y, w.y, acc);
    acc = fmaf(a.z, w.z, acc); acc = fmaf(a.w, w.w, acc);
  }
  float x2 = acc + x1[row * DIM + t];
  float e = x2 > 0.0f ? x2 : expm1f(x2);
  float mu = blockReduceSum(e, red) * (1.0f / DIM);
  float d = e - mu;
  float var = blockReduceSum(d * d, red) * (1.0f / (DIM - 1));
  float denom = sqrtf(var) + LNEPS;
  out[row * DIM + t] = alpha[t] * d / denom + bias[t];
}

// ------- K6-fast-a: logits GEMM, 128x128 tile, 8x8 micro, k-major LDS -------
__global__ __launch_bounds__(256) void k_logits2(
    const float* __restrict__ x3, const int* __restrict__ qidx,
    const int* __restrict__ kidx, float* __restrict__ logits) {
  __shared__ float As[16 * 128];   // [kk][row]
  __shared__ float Bs[16 * 128];   // [kk][col]
  __shared__ int qrow[128], krow[128];
  int c0 = blockIdx.x * 128, r0 = blockIdx.y * 128;
  int t = threadIdx.x;
  int tr = t >> 4, tc = t & 15;    // 16 x 16 thread grid; 8x8 micro-tile
  if (t < 128) qrow[t] = qidx[r0 + t];
  else krow[t - 128] = kidx[c0 + t - 128];
  float acc[8][8];
#pragma unroll
  for (int i = 0; i < 8; ++i)
#pragma unroll
    for (int j = 0; j < 8; ++j) acc[i][j] = 0.0f;

  for (int kc = 0; kc < 16; ++kc) {
    int k0 = kc * 16;
    __syncthreads();
    // stage 128x16 of A and B (k-major): i in 0..511 float4-loads per matrix
    for (int it = 0; it < 2; ++it) {
      int i = t + it * 256;
      int row = i & 127, kq = i >> 7;   // kq in 0..3
      float4 av = *(const float4*)(x3 + (size_t)qrow[row] * DIM + k0 + kq * 4);
      float4 bv = *(const float4*)(x3 + (size_t)krow[row] * DIM + k0 + kq * 4);
      As[(kq * 4 + 0) * 128 + row] = av.x; As[(kq * 4 + 1) * 128 + row] = av.y;
      As[(kq * 4 + 2) * 128 + row] = av.z; As[(kq * 4 + 3) * 128 + row] = av.w;
      Bs[(kq * 4 + 0) * 128 + row] = bv.x; Bs[(kq * 4 + 1) * 128 + row] = bv.y;
      Bs[(kq * 4 + 2) * 128 + row] = bv.z; Bs[(kq * 4 + 3) * 128 + row] = bv.w;
    }
    __syncthreads();
#pragma unroll 4
    for (int kk = 0; kk < 16; ++kk) {
      float4 a0 = *(const float4*)(As + kk * 128 + tr * 8);
      float4 a1 = *(const float4*)(As + kk * 128 + tr * 8 + 4);
      float4 b0 = *(const float4*)(Bs + kk * 128 + tc * 8);
      float4 b1 = *(const float4*)(Bs + kk * 128 + tc * 8 + 4);
      float ar[8] = {a0.x, a0.y, a0.z, a0.w, a1.x, a1.y, a1.z, a1.w};
      float br[8] = {b0.x, b0.y, b0.z, b0.w, b1.x, b1.y, b1.z, b1.w};
#pragma unroll
      for (int i = 0; i < 8; ++i)
#pragma unroll
        for (int j = 0; j < 8; ++j)
          acc[i][j] = fmaf(ar[i], br[j], acc[i][j]);
    }
  }
#pragma unroll
  for (int i = 0; i < 8; ++i) {
    float4 o0 = make_float4(acc[i][0], acc[i][1], acc[i][2], acc[i][3]);
    float4 o1 = make_float4(acc[i][4], acc[i][5], acc[i][6], acc[i][7]);
    *(float4*)(logits + (size_t)(r0 + tr * 8 + i) * NROWS + c0 + tc * 8)     = o0;
    *(float4*)(logits + (size_t)(r0 + tr * 8 + i) * NROWS + c0 + tc * 8 + 4) = o1;
  }
}

// ------- K6-fast-b: per-row finalize from materialized logits -------
__global__ __launch_bounds__(256) void k_final3(
    const float* __restrict__ logits, float* __restrict__ outp) {
  __shared__ float  sc[4096];
  __shared__ double redd[256];
  __shared__ float  red[256];
  __shared__ int    redi[256];
  __shared__ float  redp[256];
  int row = blockIdx.x, t = threadIdx.x;
  for (int c = t; c < NROWS; c += 256) sc[c] = logits[(size_t)row * NROWS + c];
  __syncthreads();
  double part = 0.0;
  for (int c = t; c < NROWS; c += 256) part += (double)sc[c];
  double S = blockReduceSumD(part, redd);
  double inv = 1.0 / S;
  float lmax = -3.402823466e38f;
  for (int c = t; c < NROWS; c += 256) {
    float z = (float)((double)sc[c] * inv);
    sc[c] = z;
    lmax = fmaxf(lmax, z);
  }
  float M = blockReduceMax(lmax, red);
  double esum = 0.0;
  for (int c = t; c < NROWS; c += 256) {
    float p = expf(sc[c] - M);
    sc[c] = p;
    esum += (double)p;
  }
  float E = (float)blockReduceSumD(esum, redd);
  uint32_t rbase = (uint32_t)row * (uint32_t)NROWS;
  float best = -3.402823466e38f; int bidx = 0x7fffffff; float bp = 0.0f;
  for (int c = t; c < NROWS; c += 256) {
    uint32_t o0, o1;
    threefry2x32(0u, 42u, 0u, rbase + (uint32_t)c, o0, o1);
    uint32_t bits = o0 ^ o1;
    float u = jax_uniform_from_bits(bits);
    float g = -logf(-logf(u));
    float p = sc[c] / E;
    float val = p + g;
    if (val > best) { best = val; bidx = c; bp = p; }
  }
  red[t] = best; redi[t] = bidx; redp[t] = bp;
  __syncthreads();
  for (int s = 128; s > 0; s >>= 1) {
    if (t < s) {
      float vb = red[t + s];
      if (vb > red[t] || (vb == red[t] && redi[t + s] < redi[t])) {
        red[t] = vb; redi[t] = redi[t + s]; redp[t] = redp[t + s];
      }
    }
    __syncthreads();
  }
  if (t == 0) {
    outp[row]         = (float)redi[0];
    outp[NROWS + row] = redp[0];
  }
}

// ------- fallback path kernels (proven) -------
__global__ void k_transpose_ke(const float* __restrict__ x3, const int* __restrict__ kidx,
                               float2* __restrict__ keT2) {
  __shared__ float tile[64 * 65];
  int cb = blockIdx.x, db = blockIdx.y;
  int t = threadIdx.x;
  for (int i = t; i < 4096; i += 256) {
    int ci = i >> 6, di = i & 63;
    int kj = kidx[cb * 64 + ci];
    tile[ci * 65 + di] = x3[(size_t)kj * DIM + db * 64 + di];
  }
  __syncthreads();
  for (int i = t; i < 2048; i += 256) {
    int di2 = i >> 6, ci = i & 63;
    keT2[(size_t)(db * 32 + di2) * NROWS + cb * 64 + ci] =
        make_float2(tile[ci * 65 + di2 * 2], tile[ci * 65 + di2 * 2 + 1]);
  }
}

#define FR 3
__global__ __launch_bounds__(256) void k_final2(
    const float* __restrict__ x3, const float2* __restrict__ keT2,
    const int* __restrict__ qidx, float* __restrict__ outp) {
  __shared__ float  slog[FR * 4096];
  __shared__ float2 sqe[FR * 128];
  __shared__ double redd[256];
  __shared__ float  red[256];
  __shared__ int    redi[256];
  __shared__ float  redp[256];
  int r0 = blockIdx.x * FR;
  int nr = NROWS - r0; if (nr > FR) nr = FR;
  int t = threadIdx.x;
  for (int i = t; i < FR * 128; i += 256) {
    int j = i >> 7, d2 = i & 127;
    if (r0 + j < NROWS) {
      int qi = qidx[r0 + j];
      sqe[j * 128 + d2] = ((const float2*)(x3 + (size_t)qi * DIM))[d2];
    } else {
      sqe[j * 128 + d2] = make_float2(0.0f, 0.0f);
    }
  }
  __syncthreads();
  for (int c = t; c < NROWS; c += 256) {
    float a0 = 0.0f, a1 = 0.0f, a2 = 0.0f;
#pragma unroll 8
    for (int d2 = 0; d2 < 128; ++d2) {
      float2 kv = keT2[(size_t)d2 * NROWS + c];
      float2 q0 = sqe[0 * 128 + d2];
      float2 q1 = sqe[1 * 128 + d2];
      float2 q2 = sqe[2 * 128 + d2];
      a0 = fmaf(q0.x, kv.x, fmaf(q0.y, kv.y, a0));
      a1 = fmaf(q1.x, kv.x, fmaf(q1.y, kv.y, a1));
      a2 = fmaf(q2.x, kv.x, fmaf(q2.y, kv.y, a2));
    }
    slog[0 * 4096 + c] = a0;
    slog[1 * 4096 + c] = a1;
    slog[2 * 4096 + c] = a2;
  }
  __syncthreads();
  for (int j = 0; j < nr; ++j) {
    int row = r0 + j;
    float* sc = &slog[j * 4096];
    double part = 0.0;
    for (int c = t; c < NROWS; c += 256) part += (double)sc[c];
    double S = blockReduceSumD(part, redd);
    double inv = 1.0 / S;
    float lmax = -3.402823466e38f;
    for (int c = t; c < NROWS; c += 256) {
      float z = (float)((double)sc[c] * inv);
      sc[c] = z;
      lmax = fmaxf(lmax, z);
    }
    float M = blockReduceMax(lmax, red);
    double esum = 0.0;
    for (int c = t; c < NROWS; c += 256) {
      float p = expf(sc[c] - M);
      sc[c] = p;
      esum += (double)p;
    }
    float E = (float)blockReduceSumD(esum, redd);
    uint32_t rbase = (uint32_t)row * (uint32_t)NROWS;
    float best = -3.402823466e38f; int bidx = 0x7fffffff; float bp = 0.0f;
    for (int c = t; c < NROWS; c += 256) {
      uint32_t o0, o1;
      threefry2x32(0u, 42u, 0u, rbase + (uint32_t)c, o0, o1);
      uint32_t bits = o0 ^ o1;
      float u = jax_uniform_from_bits(bits);
      float g = -logf(-logf(u));
      float p = sc[c] / E;
      float val = p + g;
      if (val > best) { best = val; bidx = c; bp = p; }
    }
    red[t] = best; redi[t] = bidx; redp[t] = bp;
    __syncthreads();
    for (int s = 128; s > 0; s >>= 1) {
      if (t < s) {
        float vb = red[t + s];
        if (vb > red[t] || (vb == red[t] && redi[t + s] < redi[t])) {
          red[t] = vb; redi[t] = redi[t + s]; redp[t] = redp[t + s];
        }
      }
      __syncthreads();
    }
    if (t == 0) {
      outp[row]         = (float)redi[0];
      outp[NROWS + row] = redp[0];
    }
    __syncthreads();
  }
}

extern "C" void kernel_launch(void* const* d_in, const int* in_sizes, int n_in,
                              void* d_out, int out_size, void* d_ws, size_t ws_size,
                              hipStream_t stream) {
  const float* x_input = (const float*)d_in[0];
  const void*  mask    = (const void*)d_in[1];
  const int*   qidx    = (const int*)d_in[2];
  const int*   kidx    = (const int*)d_in[3];
  const float* alpha0  = (const float*)d_in[4];
  const float* bias0   = (const float*)d_in[5];
  const float* W1      = (const float*)d_in[6];
  const float* b1      = (const float*)d_in[7];
  const float* alpha1  = (const float*)d_in[8];
  const float* bias1   = (const float*)d_in[9];
  const float* alpha2  = (const float*)d_in[10];
  const float* bias2   = (const float*)d_in[11];
  const float* Wq = (const float*)d_in[12]; const float* bq = (const float*)d_in[13];
  const float* Wk = (const float*)d_in[14]; const float* bk = (const float*)d_in[15];
  const float* Wv = (const float*)d_in[16]; const float* bv = (const float*)d_in[17];
  const float* Wo = (const float*)d_in[18]; const float* bo = (const float*)d_in[19];

  float* ws = (float*)d_ws;
  const size_t MAT  = (size_t)NROWS * DIM;        // 1M floats
  const size_t MATB = MAT * sizeof(float);        // 4 MB
  float*  x0   = ws + 0 * MAT;   // maskbits slot (x0 never materialized now)
  float*  x1   = ws + 1 * MAT;
  float*  q    = ws + 2 * MAT;
  float*  k    = ws + 3 * MAT;
  float*  v    = ws + 4 * MAT;
  float*  att  = ws + 5 * MAT;
  float*  x3   = ws + 6 * MAT;
  unsigned long long* maskbits = (unsigned long long*)x0;
  float*  out = (float*)d_out;

  bool fast = ws_size >= 23ull * MATB + 4096ull;
  float*  logits = ws + 7 * MAT;                  // 64 MB (fast)
  float2* keT2   = (float2*)(ws + 7 * MAT);       // 8 MB (fallback)
  int* mflag = fast ? (int*)(ws + 23 * MAT) : (int*)(ws + 9 * MAT);

  k_detect_mask<<<1, 256, 0, stream>>>((const uint32_t*)mask, mflag);
  k_ln_fc_elu_ln<<<NROWS, 256, 0, stream>>>(x_input, alpha0, bias0, W1, b1, alpha1, bias1, x1);
  k_mask_pack<<<NROWS, 256, 0, stream>>>(mask, mflag, maskbits);
  k_qkv2<<<dim3(NROWS / QR, 3), 256, 0, stream>>>(x1, Wq, bq, Wk, bk, Wv, bv, q, k, v);
  k_attn5<<<dim3(NROWS / 16, NHEAD), 256, 0, stream>>>(q, k, v, maskbits, att);
  k_out_ln<<<NROWS, 256, 0, stream>>>(att, Wo, bo, x1, alpha2, bias2, x3);
  if (fast) {
    k_logits2<<<dim3(NROWS / 128, NROWS / 128), 256, 0, stream>>>(x3, qidx, kidx, logits);
    k_final3<<<NROWS, 256, 0, stream>>>(logits, out);
  } else {
    k_transpose_ke<<<dim3(64, 4), 256, 0, stream>>>(x3, kidx, keT2);
    k_final2<<<(NROWS + FR - 1) / FR, 256, 0, stream>>>(x3, keT2, qidx, out);
  }
}